// Round 1
// baseline (6598.367 us; speedup 1.0000x reference)
//
#include <hip/hip_runtime.h>
#include <hip/hip_bf16.h>
#include <cmath>

constexpr int T_ = 64, B_ = 128, S_ = 128, H_ = 200, E_ = 200, A_ = 100, V_ = 10003;
constexpr int KP = 224;      // padded K (=H) for out-GEMM, multiple of 32
constexpr int VP = 10240;    // padded V, multiple of 256
constexpr int NCH = VP / 64; // 160 chunks of 64 v each

typedef __attribute__((ext_vector_type(8))) short bf16x8;
typedef __attribute__((ext_vector_type(4))) float f32x4;

// ---------------- precompute kernels ----------------

// Pack out_W^T into bf16, layout [KP/8][VP][8] so that B-fragment loads are
// contiguous 16B per lane; also zero the padded bf16 h buffer.
__global__ __launch_bounds__(256) void k_pack(const float* __restrict__ outW,
                                              __hip_bfloat16* __restrict__ wpk,
                                              __hip_bfloat16* __restrict__ hbf) {
  const int stride = gridDim.x * blockDim.x;
  const int total = (KP / 8) * VP * 8;
  for (int idx = blockIdx.x * blockDim.x + threadIdx.x; idx < total; idx += stride) {
    int kk = idx & 7;
    int v = (idx >> 3) % VP;
    int kb = idx / (8 * VP);
    int k = kb * 8 + kk;
    float val = (k < H_ && v < V_) ? outW[(size_t)v * H_ + k] : 0.f;
    wpk[idx] = __float2bfloat16(val);
  }
  for (int idx = blockIdx.x * blockDim.x + threadIdx.x; idx < B_ * KP; idx += stride)
    hbf[idx] = __float2bfloat16(0.f);
}

// ah2[b][s][a] = b2[a] + sum_h enc[s,b,h] * W2[a,h]
__global__ __launch_bounds__(256) void k_ah2(const float* __restrict__ encoder,
                                             const float* __restrict__ W2,
                                             const float* __restrict__ b2,
                                             float* __restrict__ ah2) {
  __shared__ float encL[16][200];
  const int s = blockIdx.x, b0 = blockIdx.y * 16, tid = threadIdx.x;
  for (int i = tid; i < 16 * 200; i += 256) {
    int bl = i / 200, k = i % 200;
    encL[bl][k] = encoder[((size_t)s * B_ + b0 + bl) * H_ + k];
  }
  __syncthreads();
  for (int o = tid; o < 16 * A_; o += 256) {
    int bl = o / A_, a = o % A_;
    const float* w = W2 + (size_t)a * H_;
    float acc = b2[a];
    for (int k = 0; k < H_; ++k) acc += encL[bl][k] * w[k];
    ah2[((size_t)(b0 + bl) * S_ + s) * A_ + a] = acc;
  }
}

// ah3[t][b][a] = b3[a] + sum_e emb[tok[t,b], e] * W3[a,e]
__global__ __launch_bounds__(256) void k_ah3(const int* __restrict__ tokens,
                                             const float* __restrict__ emb,
                                             const float* __restrict__ W3,
                                             const float* __restrict__ b3,
                                             float* __restrict__ ah3) {
  __shared__ float embL[16][200];
  __shared__ int tokL[16];
  const int t = blockIdx.x, b0 = blockIdx.y * 16, tid = threadIdx.x;
  if (tid < 16) tokL[tid] = tokens[t * B_ + b0 + tid];
  __syncthreads();
  for (int i = tid; i < 16 * 200; i += 256) {
    int bl = i / 200, k = i % 200;
    embL[bl][k] = emb[(size_t)tokL[bl] * E_ + k];
  }
  __syncthreads();
  for (int o = tid; o < 16 * A_; o += 256) {
    int bl = o / A_, a = o % A_;
    const float* w = W3 + (size_t)a * E_;
    float acc = b3[a];
    for (int k = 0; k < E_; ++k) acc += embL[bl][k] * w[k];
    ah3[((size_t)t * B_ + b0 + bl) * A_ + a] = acc;
  }
}

// ---------------- per-step kernels ----------------

// One block per batch row b: ah1 -> relu-attn logits -> softmax -> ctx.
__global__ __launch_bounds__(256) void k_attn(const float* __restrict__ h_src,
                                              const float* __restrict__ ah2,
                                              const float* __restrict__ ah3_t,
                                              const float* __restrict__ encoder,
                                              const float* __restrict__ W1,
                                              const float* __restrict__ b1,
                                              const float* __restrict__ attn_W,
                                              const float* __restrict__ attn_b,
                                              float* __restrict__ ctx,
                                              float* __restrict__ attn_out_t) {
  constexpr int AP = 101; // LDS pitch, coprime with 32 banks
  __shared__ float hL[H_];
  __shared__ float s1[A_];
  __shared__ float ah2L[S_ * AP];
  __shared__ float red[S_];
  __shared__ float aL[S_];
  const int b = blockIdx.x, tid = threadIdx.x;

  for (int i = tid; i < H_; i += 256) hL[i] = h_src[b * H_ + i];
  for (int i = tid; i < S_ * A_; i += 256) {
    int s = i / A_, a = i % A_;
    ah2L[s * AP + a] = ah2[(size_t)b * S_ * A_ + i];
  }
  __syncthreads();
  if (tid < A_) {
    const float* w = W1 + (size_t)tid * H_;
    float acc = b1[tid];
    for (int k = 0; k < H_; ++k) acc += hL[k] * w[k];
    s1[tid] = acc + ah3_t[b * A_ + tid];
  }
  __syncthreads();
  float lg = 0.f;
  if (tid < S_) {
    float acc = attn_b[0];
    for (int a = 0; a < A_; ++a)
      acc += fmaxf(s1[a] + ah2L[tid * AP + a], 0.f) * attn_W[a];
    lg = acc;
    red[tid] = acc;
  }
  __syncthreads();
  for (int off = 64; off > 0; off >>= 1) {
    if (tid < off) red[tid] = fmaxf(red[tid], red[tid + off]);
    __syncthreads();
  }
  float m = red[0];
  __syncthreads();
  if (tid < S_) red[tid] = expf(lg - m);
  __syncthreads();
  for (int off = 64; off > 0; off >>= 1) {
    if (tid < off) red[tid] += red[tid + off];
    __syncthreads();
  }
  float ssum = red[0];
  if (tid < S_) {
    float av = expf(lg - m) / ssum;
    aL[tid] = av;
    attn_out_t[b * S_ + tid] = av;
  }
  __syncthreads();
  if (tid < H_) {
    float c = 0.f;
    for (int s = 0; s < S_; ++s)
      c += aL[s] * encoder[((size_t)s * B_ + b) * H_ + tid];
    ctx[b * H_ + tid] = c;
  }
}

// GRU cell: block covers 8 b x 25 n. Writes fp32 h_next + bf16-packed h_next.
__global__ __launch_bounds__(256) void k_gru(const float* __restrict__ h_src,
                                             const float* __restrict__ ctx,
                                             const int* __restrict__ tok_t,
                                             const float* __restrict__ emb,
                                             const float* __restrict__ Wih,
                                             const float* __restrict__ Whh,
                                             const float* __restrict__ bih,
                                             const float* __restrict__ bhh,
                                             float* __restrict__ h_dst,
                                             __hip_bfloat16* __restrict__ hbf,
                                             float* __restrict__ out_hidden) {
  __shared__ float xe[8][200], xc[8][200], hh[8][200];
  __shared__ int tokL[8];
  const int tid = threadIdx.x;
  const int b0 = blockIdx.x * 8;
  const int n0 = blockIdx.y * 25;
  if (tid < 8) tokL[tid] = tok_t[b0 + tid];
  __syncthreads();
  for (int i = tid; i < 8 * 200; i += 256) {
    int bl = i / 200, k = i % 200;
    xe[bl][k] = emb[(size_t)tokL[bl] * E_ + k];
    xc[bl][k] = ctx[(b0 + bl) * H_ + k];
    hh[bl][k] = h_src[(b0 + bl) * H_ + k];
  }
  __syncthreads();
  if (tid < 200) {
    const int bl = tid & 7, nl = tid >> 3;
    const int n = n0 + nl;
    const int b = b0 + bl;
    const float* wr = Wih + (size_t)n * 400;
    const float* wz = Wih + (size_t)(200 + n) * 400;
    const float* wn = Wih + (size_t)(400 + n) * 400;
    const float* ur = Whh + (size_t)n * 200;
    const float* uz = Whh + (size_t)(200 + n) * 200;
    const float* un = Whh + (size_t)(400 + n) * 200;
    float ir = bih[n], iz = bih[200 + n], inn = bih[400 + n];
    float hr = bhh[n], hz = bhh[200 + n], hn = bhh[400 + n];
    for (int k = 0; k < 200; ++k) {
      float e_ = xe[bl][k], c_ = xc[bl][k], h_ = hh[bl][k];
      ir += e_ * wr[k] + c_ * wr[200 + k];
      iz += e_ * wz[k] + c_ * wz[200 + k];
      inn += e_ * wn[k] + c_ * wn[200 + k];
      hr += h_ * ur[k];
      hz += h_ * uz[k];
      hn += h_ * un[k];
    }
    float r = 1.f / (1.f + expf(-(ir + hr)));
    float z = 1.f / (1.f + expf(-(iz + hz)));
    float nn = tanhf(inn + r * hn);
    float hnew = (1.f - z) * nn + z * hh[bl][n];
    h_dst[b * H_ + n] = hnew;
    hbf[b * KP + n] = __float2bfloat16(hnew);
    if (out_hidden) out_hidden[b * H_ + n] = hnew;
  }
}

// Output projection via bf16 MFMA. pass 0: per-(chunk,b) online-softmax
// partials (no store). pass 1: recompute GEMM, write logit - lse once.
__global__ __launch_bounds__(256) void k_outgemm(const short* __restrict__ hb,
                                                 const short* __restrict__ wpk,
                                                 const float* __restrict__ outb,
                                                 float* __restrict__ pmax,
                                                 float* __restrict__ psum,
                                                 float* __restrict__ out_logp_t,
                                                 int pass) {
  const int tid = threadIdx.x;
  const int w = tid >> 6, l = tid & 63;
  const int lm = l & 15, lg = l >> 4;
  const int b0 = blockIdx.y * 32;
  const int v0 = blockIdx.x * 256 + w * 64;

  __shared__ float lseL[32];
  __shared__ float redM[32][9];
  __shared__ float mB[32];

  if (pass == 1) {
    const int b_l = tid & 31, p = tid >> 5; // 8 partials per b
    float mloc = -INFINITY;
    for (int ch = p; ch < NCH; ch += 8) mloc = fmaxf(mloc, pmax[ch * B_ + b0 + b_l]);
    redM[b_l][p] = mloc;
    __syncthreads();
    if (tid < 32) {
      float m = -INFINITY;
      for (int i = 0; i < 8; ++i) m = fmaxf(m, redM[tid][i]);
      mB[tid] = m;
    }
    __syncthreads();
    float sloc = 0.f;
    const float mm = mB[b_l];
    for (int ch = p; ch < NCH; ch += 8) {
      float pm = pmax[ch * B_ + b0 + b_l];
      sloc += expf(pm - mm) * psum[ch * B_ + b0 + b_l];
    }
    redM[b_l][p] = sloc;
    __syncthreads();
    if (tid < 32) {
      float s = 0.f;
      for (int i = 0; i < 8; ++i) s += redM[tid][i];
      lseL[tid] = mB[tid] + logf(s);
    }
    __syncthreads();
  }

  f32x4 acc[2][4] = {};
#pragma unroll
  for (int kt = 0; kt < KP / 32; ++kt) {
    const int k0 = kt * 32;
    bf16x8 af[2], bfr[4];
#pragma unroll
    for (int wm = 0; wm < 2; ++wm)
      af[wm] = *(const bf16x8*)(hb + (size_t)(b0 + wm * 16 + lm) * KP + k0 + lg * 8);
#pragma unroll
    for (int n = 0; n < 4; ++n)
      bfr[n] = *(const bf16x8*)(wpk + ((size_t)((k0 >> 3) + lg) * VP + v0 + n * 16 + lm) * 8);
#pragma unroll
    for (int wm = 0; wm < 2; ++wm)
#pragma unroll
      for (int n = 0; n < 4; ++n)
        acc[wm][n] = __builtin_amdgcn_mfma_f32_16x16x32_bf16(af[wm], bfr[n], acc[wm][n], 0, 0, 0);
  }

  int vv[4];
  float bias[4];
  bool val[4];
#pragma unroll
  for (int n = 0; n < 4; ++n) {
    vv[n] = v0 + n * 16 + lm;
    val[n] = vv[n] < V_;
    bias[n] = val[n] ? outb[vv[n]] : 0.f;
  }

  if (pass == 0) {
#pragma unroll
    for (int wm = 0; wm < 2; ++wm) {
#pragma unroll
      for (int j = 0; j < 4; ++j) {
        float m = -INFINITY;
#pragma unroll
        for (int n = 0; n < 4; ++n)
          if (val[n]) m = fmaxf(m, acc[wm][n][j] + bias[n]);
        for (int off = 8; off > 0; off >>= 1) m = fmaxf(m, __shfl_xor(m, off, 64));
        float s = 0.f;
#pragma unroll
        for (int n = 0; n < 4; ++n)
          if (val[n]) s += expf(acc[wm][n][j] + bias[n] - m);
        for (int off = 8; off > 0; off >>= 1) s += __shfl_xor(s, off, 64);
        if (lm == 0) {
          const int ch = v0 >> 6;
          const int bidx = b0 + wm * 16 + lg * 4 + j;
          pmax[ch * B_ + bidx] = m;
          psum[ch * B_ + bidx] = s;
        }
      }
    }
  } else {
#pragma unroll
    for (int wm = 0; wm < 2; ++wm) {
#pragma unroll
      for (int j = 0; j < 4; ++j) {
        const int bidx = b0 + wm * 16 + lg * 4 + j;
        const float ls = lseL[wm * 16 + lg * 4 + j];
#pragma unroll
        for (int n = 0; n < 4; ++n)
          if (val[n]) out_logp_t[(size_t)bidx * V_ + vv[n]] = acc[wm][n][j] + bias[n] - ls;
      }
    }
  }
}

// ---------------- host launch ----------------

extern "C" void kernel_launch(void* const* d_in, const int* in_sizes, int n_in,
                              void* d_out, int out_size, void* d_ws, size_t ws_size,
                              hipStream_t stream) {
  (void)in_sizes; (void)n_in; (void)out_size; (void)ws_size;
  const int* tokens = (const int*)d_in[0];
  const float* hidden0 = (const float*)d_in[1];
  const float* encoder = (const float*)d_in[2];
  const float* emb = (const float*)d_in[3];
  const float* W1 = (const float*)d_in[4];
  const float* b1 = (const float*)d_in[5];
  const float* W2 = (const float*)d_in[6];
  const float* b2 = (const float*)d_in[7];
  const float* W3 = (const float*)d_in[8];
  const float* b3 = (const float*)d_in[9];
  const float* attn_W = (const float*)d_in[10];
  const float* attn_b = (const float*)d_in[11];
  const float* Wih = (const float*)d_in[12];
  const float* Whh = (const float*)d_in[13];
  const float* bih = (const float*)d_in[14];
  const float* bhh = (const float*)d_in[15];
  const float* outW = (const float*)d_in[16];
  const float* outb = (const float*)d_in[17];

  float* out_logp = (float*)d_out;
  float* out_hidden = out_logp + (size_t)T_ * B_ * V_;
  float* out_attn = out_hidden + (size_t)B_ * H_;

  float* ws = (float*)d_ws;
  float* ah2w = ws;                                   // B*S*A
  float* ah3w = ah2w + (size_t)B_ * S_ * A_;          // T*B*A
  float* ctxw = ah3w + (size_t)T_ * B_ * A_;          // B*H
  float* hbuf = ctxw + (size_t)B_ * H_;               // 2*B*H ping-pong
  float* pmaxw = hbuf + (size_t)2 * B_ * H_;          // NCH*B
  float* psumw = pmaxw + (size_t)NCH * B_;            // NCH*B
  __hip_bfloat16* hbfw = (__hip_bfloat16*)(psumw + (size_t)NCH * B_); // B*KP
  __hip_bfloat16* wpkw = hbfw + (size_t)B_ * KP;      // (KP/8)*VP*8

  k_pack<<<512, 256, 0, stream>>>(outW, wpkw, hbfw);
  k_ah2<<<dim3(S_, B_ / 16), 256, 0, stream>>>(encoder, W2, b2, ah2w);
  k_ah3<<<dim3(T_, B_ / 16), 256, 0, stream>>>(tokens, emb, W3, b3, ah3w);

  for (int t = 0; t < T_; ++t) {
    const float* h_src = (t == 0) ? hidden0 : hbuf + (t & 1) * B_ * H_;
    float* h_dst = hbuf + ((t + 1) & 1) * B_ * H_;

    k_attn<<<B_, 256, 0, stream>>>(h_src, ah2w, ah3w + (size_t)t * B_ * A_, encoder,
                                   W1, b1, attn_W, attn_b, ctxw,
                                   out_attn + (size_t)t * B_ * S_);
    k_gru<<<dim3(B_ / 8, 8), 256, 0, stream>>>(h_src, ctxw, tokens + t * B_, emb,
                                               Wih, Whh, bih, bhh, h_dst, hbfw,
                                               (t == T_ - 1) ? out_hidden : nullptr);
    k_outgemm<<<dim3(VP / 256, B_ / 32), 256, 0, stream>>>(
        (const short*)hbfw, (const short*)wpkw, outb, pmaxw, psumw,
        out_logp + (size_t)t * B_ * V_, 0);
    k_outgemm<<<dim3(VP / 256, B_ / 32), 256, 0, stream>>>(
        (const short*)hbfw, (const short*)wpkw, outb, pmaxw, psumw,
        out_logp + (size_t)t * B_ * V_, 1);
  }
}

// Round 3
// 4519.619 us; speedup vs baseline: 1.4599x; 1.4599x over previous
//
#include <hip/hip_runtime.h>
#include <hip/hip_bf16.h>
#include <cmath>

constexpr int T_ = 64, B_ = 128, S_ = 128, H_ = 200, E_ = 200, A_ = 100, V_ = 10003;
constexpr int KP = 224;        // padded K (=H), multiple of 32
constexpr int VP = 10240;      // padded V, multiple of 256
constexpr int MROWS = T_ * B_; // 8192 rows in the batched output GEMM
constexpr int NCB = VP / 256;  // 40 column-blocks

typedef __attribute__((ext_vector_type(8))) short bf16x8;
typedef __attribute__((ext_vector_type(4))) float f32x4;

// ---------------- precompute kernels ----------------

// Pack out_W^T into bf16 layout [KP/8][VP][8]; zero the padded bf16 H buffer.
__global__ __launch_bounds__(256) void k_pack(const float* __restrict__ outW,
                                              __hip_bfloat16* __restrict__ wpk,
                                              __hip_bfloat16* __restrict__ hall) {
  const int stride = gridDim.x * blockDim.x;
  const int total = (KP / 8) * VP * 8;
  for (int idx = blockIdx.x * blockDim.x + threadIdx.x; idx < total; idx += stride) {
    int kk = idx & 7;
    int v = (idx >> 3) % VP;
    int kb = idx / (8 * VP);
    int k = kb * 8 + kk;
    float val = (k < H_ && v < V_) ? outW[(size_t)v * H_ + k] : 0.f;
    wpk[idx] = __float2bfloat16(val);
  }
  const __hip_bfloat16 z = __float2bfloat16(0.f);
  for (int idx = blockIdx.x * blockDim.x + threadIdx.x; idx < MROWS * KP; idx += stride)
    hall[idx] = z;
}

// ah2[b][s][a] = b2[a] + sum_h enc[s,b,h] * W2[a,h]
__global__ __launch_bounds__(256) void k_ah2(const float* __restrict__ encoder,
                                             const float* __restrict__ W2,
                                             const float* __restrict__ b2,
                                             float* __restrict__ ah2) {
  __shared__ float encL[16][200];
  const int s = blockIdx.x, b0 = blockIdx.y * 16, tid = threadIdx.x;
  for (int i = tid; i < 16 * 200; i += 256) {
    int bl = i / 200, k = i % 200;
    encL[bl][k] = encoder[((size_t)s * B_ + b0 + bl) * H_ + k];
  }
  __syncthreads();
  for (int o = tid; o < 16 * A_; o += 256) {
    int bl = o / A_, a = o % A_;
    const float* w = W2 + (size_t)a * H_;
    float acc = b2[a];
    for (int k = 0; k < H_; ++k) acc += encL[bl][k] * w[k];
    ah2[((size_t)(b0 + bl) * S_ + s) * A_ + a] = acc;
  }
}

// ah3[t][b][a] = b3[a] + sum_e emb[tok[t,b], e] * W3[a,e]
__global__ __launch_bounds__(256) void k_ah3(const int* __restrict__ tokens,
                                             const float* __restrict__ emb,
                                             const float* __restrict__ W3,
                                             const float* __restrict__ b3,
                                             float* __restrict__ ah3) {
  __shared__ float embL[16][200];
  __shared__ int tokL[16];
  const int t = blockIdx.x, b0 = blockIdx.y * 16, tid = threadIdx.x;
  if (tid < 16) tokL[tid] = tokens[t * B_ + b0 + tid];
  __syncthreads();
  for (int i = tid; i < 16 * 200; i += 256) {
    int bl = i / 200, k = i % 200;
    embL[bl][k] = emb[(size_t)tokL[bl] * E_ + k];
  }
  __syncthreads();
  for (int o = tid; o < 16 * A_; o += 256) {
    int bl = o / A_, a = o % A_;
    const float* w = W3 + (size_t)a * E_;
    float acc = b3[a];
    for (int k = 0; k < E_; ++k) acc += embL[bl][k] * w[k];
    ah3[((size_t)t * B_ + b0 + bl) * A_ + a] = acc;
  }
}

// ---------------- fused per-step kernel: attention + GRU ----------------
// One block per batch row b. ctx is passed attn->GRU through LDS.
__global__ __launch_bounds__(256) void k_step(const float* __restrict__ h_src,
                                              const float* __restrict__ ah2,
                                              const float* __restrict__ ah3_t,
                                              const float* __restrict__ encoder,
                                              const float* __restrict__ W1,
                                              const float* __restrict__ b1,
                                              const float* __restrict__ attn_W,
                                              const float* __restrict__ attn_b,
                                              const int* __restrict__ tok_t,
                                              const float* __restrict__ emb,
                                              const float* __restrict__ Wih,
                                              const float* __restrict__ Whh,
                                              const float* __restrict__ bih,
                                              const float* __restrict__ bhh,
                                              float* __restrict__ h_dst,
                                              __hip_bfloat16* __restrict__ hall_t,
                                              float* __restrict__ out_hidden,
                                              float* __restrict__ attn_out_t) {
  constexpr int AP = 101; // LDS pitch for ah2 tile
  __shared__ __align__(16) float hL[H_];
  __shared__ __align__(16) float xe[E_];
  __shared__ __align__(16) float xc[H_];
  __shared__ float s1[A_];
  __shared__ float ah2L[S_ * AP];
  __shared__ float red[S_];
  __shared__ float aL[S_];
  const int b = blockIdx.x, tid = threadIdx.x;
  const int tok = tok_t[b];

  for (int i = tid; i < H_; i += 256) hL[i] = h_src[b * H_ + i];
  for (int i = tid; i < E_; i += 256) xe[i] = emb[(size_t)tok * E_ + i];
  for (int i = tid; i < S_ * A_; i += 256) {
    int s = i / A_, a = i % A_;
    ah2L[s * AP + a] = ah2[(size_t)b * S_ * A_ + i];
  }
  __syncthreads();

  // ah1 + ah3
  if (tid < A_) {
    const float* w = W1 + (size_t)tid * H_;
    float acc = b1[tid];
    for (int k = 0; k < H_; ++k) acc += hL[k] * w[k];
    s1[tid] = acc + ah3_t[b * A_ + tid];
  }
  __syncthreads();

  // relu-attn logits
  float lgv = 0.f;
  if (tid < S_) {
    float acc = attn_b[0];
    for (int a = 0; a < A_; ++a)
      acc += fmaxf(s1[a] + ah2L[tid * AP + a], 0.f) * attn_W[a];
    lgv = acc;
    red[tid] = acc;
  }
  __syncthreads();
  for (int off = 64; off > 0; off >>= 1) {
    if (tid < off) red[tid] = fmaxf(red[tid], red[tid + off]);
    __syncthreads();
  }
  float m = red[0];
  __syncthreads();
  if (tid < S_) red[tid] = expf(lgv - m);
  __syncthreads();
  for (int off = 64; off > 0; off >>= 1) {
    if (tid < off) red[tid] += red[tid + off];
    __syncthreads();
  }
  float ssum = red[0];
  if (tid < S_) {
    float av = expf(lgv - m) / ssum;
    aL[tid] = av;
    attn_out_t[b * S_ + tid] = av;
  }
  __syncthreads();

  // ctx -> LDS
  if (tid < H_) {
    float c = 0.f;
    for (int s = 0; s < S_; ++s)
      c += aL[s] * encoder[((size_t)s * B_ + b) * H_ + tid];
    xc[tid] = c;
  }
  __syncthreads();

  // GRU: thread n computes gates r,z,n for output n
  if (tid < H_) {
    const int n = tid;
    const float4* wr = (const float4*)(Wih + (size_t)n * 400);
    const float4* wz = (const float4*)(Wih + (size_t)(200 + n) * 400);
    const float4* wn = (const float4*)(Wih + (size_t)(400 + n) * 400);
    const float4* ur = (const float4*)(Whh + (size_t)n * 200);
    const float4* uz = (const float4*)(Whh + (size_t)(200 + n) * 200);
    const float4* un = (const float4*)(Whh + (size_t)(400 + n) * 200);
    float ir = bih[n], iz = bih[200 + n], inn = bih[400 + n];
    float hr = bhh[n], hz = bhh[200 + n], hn = bhh[400 + n];
#pragma unroll 5
    for (int k4 = 0; k4 < 50; ++k4) {
      float4 e4 = *(const float4*)&xe[k4 * 4];
      float4 c4 = *(const float4*)&xc[k4 * 4];
      float4 h4 = *(const float4*)&hL[k4 * 4];
      float4 w;
      w = wr[k4];      ir += e4.x * w.x + e4.y * w.y + e4.z * w.z + e4.w * w.w;
      w = wr[50 + k4]; ir += c4.x * w.x + c4.y * w.y + c4.z * w.z + c4.w * w.w;
      w = wz[k4];      iz += e4.x * w.x + e4.y * w.y + e4.z * w.z + e4.w * w.w;
      w = wz[50 + k4]; iz += c4.x * w.x + c4.y * w.y + c4.z * w.z + c4.w * w.w;
      w = wn[k4];      inn += e4.x * w.x + e4.y * w.y + e4.z * w.z + e4.w * w.w;
      w = wn[50 + k4]; inn += c4.x * w.x + c4.y * w.y + c4.z * w.z + c4.w * w.w;
      w = ur[k4];      hr += h4.x * w.x + h4.y * w.y + h4.z * w.z + h4.w * w.w;
      w = uz[k4];      hz += h4.x * w.x + h4.y * w.y + h4.z * w.z + h4.w * w.w;
      w = un[k4];      hn += h4.x * w.x + h4.y * w.y + h4.z * w.z + h4.w * w.w;
    }
    float r = 1.f / (1.f + expf(-(ir + hr)));
    float z = 1.f / (1.f + expf(-(iz + hz)));
    float nn = tanhf(inn + r * hn);
    float hnew = (1.f - z) * nn + z * hL[n];
    h_dst[b * H_ + n] = hnew;
    hall_t[(size_t)b * KP + n] = __float2bfloat16(hnew);
    if (out_hidden) out_hidden[b * H_ + n] = hnew;
  }
}

// ---------------- batched output GEMM + log-softmax ----------------
// pass 0: per-(256-col block, row) online-softmax partials. 64-row M-tile.
__global__ __launch_bounds__(256) void k_big0(const short* __restrict__ hb,
                                              const short* __restrict__ wpk,
                                              const float* __restrict__ outb,
                                              float* __restrict__ pmax,
                                              float* __restrict__ psum) {
  const int tid = threadIdx.x;
  const int w = tid >> 6, l = tid & 63;
  const int lm = l & 15, lg = l >> 4;
  const int r0 = blockIdx.y * 64;
  const int v0 = blockIdx.x * 256 + w * 64;

  f32x4 acc[4][4] = {};
#pragma unroll
  for (int kt = 0; kt < KP / 32; ++kt) {
    const int k0 = kt * 32;
    bf16x8 af[4], bfr[4];
#pragma unroll
    for (int wm = 0; wm < 4; ++wm)
      af[wm] = *(const bf16x8*)(hb + (size_t)(r0 + wm * 16 + lm) * KP + k0 + lg * 8);
#pragma unroll
    for (int n = 0; n < 4; ++n)
      bfr[n] = *(const bf16x8*)(wpk + ((size_t)((k0 >> 3) + lg) * VP + v0 + n * 16 + lm) * 8);
#pragma unroll
    for (int wm = 0; wm < 4; ++wm)
#pragma unroll
      for (int n = 0; n < 4; ++n)
        acc[wm][n] = __builtin_amdgcn_mfma_f32_16x16x32_bf16(af[wm], bfr[n], acc[wm][n], 0, 0, 0);
  }

  int vv[4]; float bias[4]; bool val[4];
#pragma unroll
  for (int n = 0; n < 4; ++n) {
    vv[n] = v0 + n * 16 + lm;
    val[n] = vv[n] < V_;
    bias[n] = val[n] ? outb[vv[n]] : 0.f;
  }

  __shared__ float smax[4][64], ssum[4][64];
#pragma unroll
  for (int wm = 0; wm < 4; ++wm) {
#pragma unroll
    for (int j = 0; j < 4; ++j) {
      float mv = -INFINITY;
#pragma unroll
      for (int n = 0; n < 4; ++n)
        if (val[n]) mv = fmaxf(mv, acc[wm][n][j] + bias[n]);
      for (int off = 8; off > 0; off >>= 1) mv = fmaxf(mv, __shfl_xor(mv, off, 64));
      float sv = 0.f;
#pragma unroll
      for (int n = 0; n < 4; ++n)
        if (val[n]) sv += expf(acc[wm][n][j] + bias[n] - mv);
      for (int off = 8; off > 0; off >>= 1) sv += __shfl_xor(sv, off, 64);
      if (lm == 0) {
        smax[w][wm * 16 + lg * 4 + j] = mv;
        ssum[w][wm * 16 + lg * 4 + j] = sv;
      }
    }
  }
  __syncthreads();
  if (tid < 64) {
    float mv = -INFINITY;
    for (int ww = 0; ww < 4; ++ww) mv = fmaxf(mv, smax[ww][tid]);
    float sv = 0.f;
    for (int ww = 0; ww < 4; ++ww) {
      float sw = ssum[ww][tid];
      if (sw > 0.f) sv += expf(smax[ww][tid] - mv) * sw;
    }
    pmax[(size_t)blockIdx.x * MROWS + r0 + tid] = mv;
    psum[(size_t)blockIdx.x * MROWS + r0 + tid] = sv;
  }
}

// reduce 40 chunk-partials -> lse per row
__global__ __launch_bounds__(256) void k_lse(const float* __restrict__ pmax,
                                             const float* __restrict__ psum,
                                             float* __restrict__ lse) {
  const int r = blockIdx.x * 256 + threadIdx.x;
  float mv = -INFINITY;
  for (int c = 0; c < NCB; ++c) mv = fmaxf(mv, pmax[(size_t)c * MROWS + r]);
  float sv = 0.f;
  for (int c = 0; c < NCB; ++c) {
    float sw = psum[(size_t)c * MROWS + r];
    if (sw > 0.f) sv += expf(pmax[(size_t)c * MROWS + r] - mv) * sw;
  }
  lse[r] = mv + logf(sv);
}

// pass 1: recompute GEMM, write logit - lse (single write of the 328 MB output)
__global__ __launch_bounds__(256) void k_big1(const short* __restrict__ hb,
                                              const short* __restrict__ wpk,
                                              const float* __restrict__ outb,
                                              const float* __restrict__ lse,
                                              float* __restrict__ out_logp) {
  const int tid = threadIdx.x;
  const int w = tid >> 6, l = tid & 63;
  const int lm = l & 15, lg = l >> 4;
  const int r0 = blockIdx.y * 64;
  const int v0 = blockIdx.x * 256 + w * 64;

  __shared__ float lseL[64];
  if (tid < 64) lseL[tid] = lse[r0 + tid];

  f32x4 acc[4][4] = {};
#pragma unroll
  for (int kt = 0; kt < KP / 32; ++kt) {
    const int k0 = kt * 32;
    bf16x8 af[4], bfr[4];
#pragma unroll
    for (int wm = 0; wm < 4; ++wm)
      af[wm] = *(const bf16x8*)(hb + (size_t)(r0 + wm * 16 + lm) * KP + k0 + lg * 8);
#pragma unroll
    for (int n = 0; n < 4; ++n)
      bfr[n] = *(const bf16x8*)(wpk + ((size_t)((k0 >> 3) + lg) * VP + v0 + n * 16 + lm) * 8);
#pragma unroll
    for (int wm = 0; wm < 4; ++wm)
#pragma unroll
      for (int n = 0; n < 4; ++n)
        acc[wm][n] = __builtin_amdgcn_mfma_f32_16x16x32_bf16(af[wm], bfr[n], acc[wm][n], 0, 0, 0);
  }

  int vv[4]; float bias[4]; bool val[4];
#pragma unroll
  for (int n = 0; n < 4; ++n) {
    vv[n] = v0 + n * 16 + lm;
    val[n] = vv[n] < V_;
    bias[n] = val[n] ? outb[vv[n]] : 0.f;
  }
  __syncthreads();
#pragma unroll
  for (int wm = 0; wm < 4; ++wm) {
#pragma unroll
    for (int j = 0; j < 4; ++j) {
      const int row = r0 + wm * 16 + lg * 4 + j;
      const float ls = lseL[wm * 16 + lg * 4 + j];
#pragma unroll
      for (int n = 0; n < 4; ++n)
        if (val[n]) out_logp[(size_t)row * V_ + vv[n]] = acc[wm][n][j] + bias[n] - ls;
    }
  }
}

// ---------------- host launch ----------------

extern "C" void kernel_launch(void* const* d_in, const int* in_sizes, int n_in,
                              void* d_out, int out_size, void* d_ws, size_t ws_size,
                              hipStream_t stream) {
  (void)in_sizes; (void)n_in; (void)out_size; (void)ws_size;
  const int* tokens = (const int*)d_in[0];
  const float* hidden0 = (const float*)d_in[1];
  const float* encoder = (const float*)d_in[2];
  const float* emb = (const float*)d_in[3];
  const float* W1 = (const float*)d_in[4];
  const float* b1 = (const float*)d_in[5];
  const float* W2 = (const float*)d_in[6];
  const float* b2 = (const float*)d_in[7];
  const float* W3 = (const float*)d_in[8];
  const float* b3 = (const float*)d_in[9];
  const float* attn_W = (const float*)d_in[10];
  const float* attn_b = (const float*)d_in[11];
  const float* Wih = (const float*)d_in[12];
  const float* Whh = (const float*)d_in[13];
  const float* bih = (const float*)d_in[14];
  const float* bhh = (const float*)d_in[15];
  const float* outW = (const float*)d_in[16];
  const float* outb = (const float*)d_in[17];

  float* out_logp = (float*)d_out;                       // [T*B, V]
  float* out_hidden = out_logp + (size_t)T_ * B_ * V_;   // [B, H]
  float* out_attn = out_hidden + (size_t)B_ * H_;        // [T, B, S]

  float* ws = (float*)d_ws;
  float* ah2w = ws;                                      // B*S*A
  float* ah3w = ah2w + (size_t)B_ * S_ * A_;             // T*B*A
  float* hbuf = ah3w + (size_t)T_ * B_ * A_;             // 2*B*H ping-pong
  float* pmaxw = hbuf + (size_t)2 * B_ * H_;             // NCB*MROWS
  float* psumw = pmaxw + (size_t)NCB * MROWS;            // NCB*MROWS
  float* lsew = psumw + (size_t)NCB * MROWS;             // MROWS
  __hip_bfloat16* hallw = (__hip_bfloat16*)(lsew + MROWS);   // MROWS*KP bf16
  __hip_bfloat16* wpkw = hallw + (size_t)MROWS * KP;         // (KP/8)*VP*8 bf16

  k_pack<<<512, 256, 0, stream>>>(outW, wpkw, hallw);
  k_ah2<<<dim3(S_, B_ / 16), 256, 0, stream>>>(encoder, W2, b2, ah2w);
  k_ah3<<<dim3(T_, B_ / 16), 256, 0, stream>>>(tokens, emb, W3, b3, ah3w);

  for (int t = 0; t < T_; ++t) {
    const float* h_src = (t == 0) ? hidden0 : hbuf + (t & 1) * B_ * H_;
    float* h_dst = hbuf + ((t + 1) & 1) * B_ * H_;
    k_step<<<B_, 256, 0, stream>>>(h_src, ah2w, ah3w + (size_t)t * B_ * A_, encoder,
                                   W1, b1, attn_W, attn_b, tokens + t * B_, emb,
                                   Wih, Whh, bih, bhh, h_dst,
                                   hallw + (size_t)t * B_ * KP,
                                   (t == T_ - 1) ? out_hidden : nullptr,
                                   out_attn + (size_t)t * B_ * S_);
  }

  k_big0<<<dim3(NCB, MROWS / 64), 256, 0, stream>>>((const short*)hallw, (const short*)wpkw,
                                                    outb, pmaxw, psumw);
  k_lse<<<MROWS / 256, 256, 0, stream>>>(pmaxw, psumw, lsew);
  k_big1<<<dim3(NCB, MROWS / 64), 256, 0, stream>>>((const short*)hallw, (const short*)wpkw,
                                                    outb, lsew, out_logp);
}

// Round 4
// 3028.636 us; speedup vs baseline: 2.1787x; 1.4923x over previous
//
#include <hip/hip_runtime.h>
#include <hip/hip_bf16.h>
#include <cmath>

constexpr int T_ = 64, B_ = 128, S_ = 128, H_ = 200, E_ = 200, A_ = 100, V_ = 10003;
constexpr int KP = 224;        // padded K (=H), multiple of 32
constexpr int VP = 10240;      // padded V, multiple of 256
constexpr int MROWS = T_ * B_; // 8192 rows in the batched output GEMM
constexpr int NCB = VP / 256;  // 40 column-blocks
constexpr int G3 = 3 * H_;     // 600 gate rows
constexpr int EH = E_ + H_;    // 400

typedef __attribute__((ext_vector_type(8))) short bf16x8;
typedef __attribute__((ext_vector_type(4))) float f32x4;

__device__ __forceinline__ float bfu(short u) {
  union { unsigned int i; float f; } c;
  c.i = ((unsigned int)(unsigned short)u) << 16;
  return c.f;
}

// ---------------- precompute kernels ----------------

// Pack out_W^T -> bf16 [KP/8][VP][8]; zero padded hall; pack W1/Wih/Whh -> bf16.
__global__ __launch_bounds__(256) void k_pack(const float* __restrict__ outW,
                                              const float* __restrict__ W1,
                                              const float* __restrict__ Wih,
                                              const float* __restrict__ Whh,
                                              __hip_bfloat16* __restrict__ wpk,
                                              __hip_bfloat16* __restrict__ hall,
                                              __hip_bfloat16* __restrict__ W1b,
                                              __hip_bfloat16* __restrict__ Wihb,
                                              __hip_bfloat16* __restrict__ Whhb) {
  const int stride = gridDim.x * blockDim.x;
  const int tid0 = blockIdx.x * blockDim.x + threadIdx.x;
  const int total = (KP / 8) * VP * 8;
  for (int idx = tid0; idx < total; idx += stride) {
    int kk = idx & 7;
    int v = (idx >> 3) % VP;
    int kb = idx / (8 * VP);
    int k = kb * 8 + kk;
    float val = (k < H_ && v < V_) ? outW[(size_t)v * H_ + k] : 0.f;
    wpk[idx] = __float2bfloat16(val);
  }
  const __hip_bfloat16 z = __float2bfloat16(0.f);
  for (int idx = tid0; idx < MROWS * KP; idx += stride) hall[idx] = z;
  for (int idx = tid0; idx < A_ * H_; idx += stride) W1b[idx] = __float2bfloat16(W1[idx]);
  for (int idx = tid0; idx < G3 * EH; idx += stride) Wihb[idx] = __float2bfloat16(Wih[idx]);
  for (int idx = tid0; idx < G3 * H_; idx += stride) Whhb[idx] = __float2bfloat16(Whh[idx]);
}

// ah2[b][s][a] = b2[a] + sum_h enc[s,b,h] * W2[a,h]
__global__ __launch_bounds__(256) void k_ah2(const float* __restrict__ encoder,
                                             const float* __restrict__ W2,
                                             const float* __restrict__ b2,
                                             float* __restrict__ ah2) {
  __shared__ float encL[16][200];
  const int s = blockIdx.x, b0 = blockIdx.y * 16, tid = threadIdx.x;
  for (int i = tid; i < 16 * 200; i += 256) {
    int bl = i / 200, k = i % 200;
    encL[bl][k] = encoder[((size_t)s * B_ + b0 + bl) * H_ + k];
  }
  __syncthreads();
  for (int o = tid; o < 16 * A_; o += 256) {
    int bl = o / A_, a = o % A_;
    const float* w = W2 + (size_t)a * H_;
    float acc = b2[a];
    for (int k = 0; k < H_; ++k) acc += encL[bl][k] * w[k];
    ah2[((size_t)(b0 + bl) * S_ + s) * A_ + a] = acc;
  }
}

// ah3[t][b][a] = b3[a] + sum_e emb[tok[t,b], e] * W3[a,e]
__global__ __launch_bounds__(256) void k_ah3(const int* __restrict__ tokens,
                                             const float* __restrict__ emb,
                                             const float* __restrict__ W3,
                                             const float* __restrict__ b3,
                                             float* __restrict__ ah3) {
  __shared__ float embL[16][200];
  __shared__ int tokL[16];
  const int t = blockIdx.x, b0 = blockIdx.y * 16, tid = threadIdx.x;
  if (tid < 16) tokL[tid] = tokens[t * B_ + b0 + tid];
  __syncthreads();
  for (int i = tid; i < 16 * 200; i += 256) {
    int bl = i / 200, k = i % 200;
    embL[bl][k] = emb[(size_t)tokL[bl] * E_ + k];
  }
  __syncthreads();
  for (int o = tid; o < 16 * A_; o += 256) {
    int bl = o / A_, a = o % A_;
    const float* w = W3 + (size_t)a * E_;
    float acc = b3[a];
    for (int k = 0; k < E_; ++k) acc += embL[bl][k] * w[k];
    ah3[((size_t)t * B_ + b0 + bl) * A_ + a] = acc;
  }
}

// ---------------- persistent recurrence kernel ----------------
// One block per batch element b; full t-loop inside. No cross-block deps.
__global__ __launch_bounds__(512) void k_recur(const float* __restrict__ hidden0,
                                               const float* __restrict__ ah2,
                                               const float* __restrict__ ah3,
                                               const float* __restrict__ encoder,
                                               const __hip_bfloat16* __restrict__ W1b,
                                               const float* __restrict__ b1,
                                               const float* __restrict__ attn_W,
                                               const float* __restrict__ attn_b,
                                               const int* __restrict__ tokens,
                                               const float* __restrict__ emb,
                                               const __hip_bfloat16* __restrict__ Wihb,
                                               const __hip_bfloat16* __restrict__ Whhb,
                                               const float* __restrict__ bih,
                                               const float* __restrict__ bhh,
                                               __hip_bfloat16* __restrict__ hall,
                                               float* __restrict__ out_hidden,
                                               float* __restrict__ out_attn) {
  constexpr int AP = 101; // pitch: stride 101 mod 32 = 5, gcd(5,32)=1 -> conflict-free
  __shared__ float ah2L[S_ * AP];          // 51.7 KB, resident across all steps
  __shared__ __align__(16) float hbuf[2][H_];
  __shared__ __align__(16) float xe[E_];
  __shared__ __align__(16) float xc[H_];
  __shared__ float s1[A_];
  __shared__ float aW[A_];
  __shared__ float aL[S_];
  __shared__ float red[8];
  __shared__ float giP[2 * G3];            // per-half partials of x @ Wih^T
  __shared__ float gh[G3];

  const int b = blockIdx.x, tid = threadIdx.x;
  const int lane = tid & 63;

  // one-time preload
  for (int i = tid; i < S_ * A_; i += 512) {
    int s = i / A_, a = i - s * A_;
    ah2L[s * AP + a] = ah2[(size_t)b * S_ * A_ + i];
  }
  for (int i = tid; i < H_; i += 512) hbuf[0][i] = hidden0[b * H_ + i];
  for (int i = tid; i < A_; i += 512) aW[i] = attn_W[i];
  const float ab = attn_b[0];
  __syncthreads();

  int cur = 0;
  for (int t = 0; t < T_; ++t) {
    const int tok = tokens[t * B_ + b];
    // ---- phase 1: xe load (tid<200)  ||  s1 = h@W1^T + b1 + ah3 (256<=tid<356)
    if (tid < E_) {
      xe[tid] = emb[(size_t)tok * E_ + tid];
    } else if (tid >= 256 && tid < 256 + A_) {
      const int a = tid - 256;
      const bf16x8* w = (const bf16x8*)(W1b + (size_t)a * H_);
      float acc = 0.f;
#pragma unroll
      for (int k8 = 0; k8 < H_ / 8; ++k8) {
        bf16x8 w8 = w[k8];
#pragma unroll
        for (int j = 0; j < 8; ++j) acc += bfu(w8[j]) * hbuf[cur][k8 * 8 + j];
      }
      s1[a] = acc + b1[a] + ah3[((size_t)t * B_ + b) * A_ + a];
    }
    __syncthreads();

    // ---- phase 2: relu-attn logits + softmax (tid<128, waves 0-1)
    float p = -INFINITY;
    if (tid < S_) {
      float acc = ab;
#pragma unroll 4
      for (int a = 0; a < A_; ++a)
        acc += fmaxf(s1[a] + ah2L[tid * AP + a], 0.f) * aW[a];
      p = acc;
    }
    float m = p;
#pragma unroll
    for (int off = 32; off > 0; off >>= 1) m = fmaxf(m, __shfl_xor(m, off, 64));
    if (tid < S_ && lane == 0) red[tid >> 6] = m;
    __syncthreads();
    const float M = fmaxf(red[0], red[1]);
    float ev = (tid < S_) ? expf(p - M) : 0.f;
    float sm = ev;
#pragma unroll
    for (int off = 32; off > 0; off >>= 1) sm += __shfl_xor(sm, off, 64);
    if (tid < S_ && lane == 0) red[4 + (tid >> 6)] = sm;
    __syncthreads();
    const float SS = red[4] + red[5];
    if (tid < S_) {
      float av = ev / SS;
      aL[tid] = av;
      out_attn[((size_t)t * B_ + b) * S_ + tid] = av;
    }
    __syncthreads();

    // ---- phase 3: ctx (tid<200): xc[n] = sum_s aL[s] * enc[s,b,n]
    if (tid < H_) {
      float c = 0.f;
#pragma unroll 8
      for (int s = 0; s < S_; ++s)
        c += aL[s] * encoder[((size_t)s * B_ + b) * H_ + tid];
      xc[tid] = c;
    }
    __syncthreads();

    // ---- phase 4: 1800 balanced dot-units of length 200
    //   u < 2*G3:  giP[u] = (u&1 ? xc : xe) . Wihb[u>>1][half*200 ..]
    //   else    :  gh[u-2*G3] = h . Whhb[row]
    for (int u = tid; u < 2 * G3 + G3; u += 512) {
      if (u < 2 * G3) {
        const int r = u >> 1, half = u & 1;
        const bf16x8* w = (const bf16x8*)(Wihb + (size_t)r * EH + half * H_);
        const float* x = half ? xc : xe;
        float acc = 0.f;
#pragma unroll
        for (int k8 = 0; k8 < H_ / 8; ++k8) {
          bf16x8 w8 = w[k8];
#pragma unroll
          for (int j = 0; j < 8; ++j) acc += bfu(w8[j]) * x[k8 * 8 + j];
        }
        giP[u] = acc;
      } else {
        const int r = u - 2 * G3;
        const bf16x8* w = (const bf16x8*)(Whhb + (size_t)r * H_);
        float acc = 0.f;
#pragma unroll
        for (int k8 = 0; k8 < H_ / 8; ++k8) {
          bf16x8 w8 = w[k8];
#pragma unroll
          for (int j = 0; j < 8; ++j) acc += bfu(w8[j]) * hbuf[cur][k8 * 8 + j];
        }
        gh[r] = acc;
      }
    }
    __syncthreads();

    // ---- phase 5: gates (tid<200)
    if (tid < H_) {
      const int n = tid;
      const float gir = giP[2 * n] + giP[2 * n + 1] + bih[n];
      const float giz = giP[2 * (200 + n)] + giP[2 * (200 + n) + 1] + bih[200 + n];
      const float gin = giP[2 * (400 + n)] + giP[2 * (400 + n) + 1] + bih[400 + n];
      const float ghr = gh[n] + bhh[n];
      const float ghz = gh[200 + n] + bhh[200 + n];
      const float ghn = gh[400 + n] + bhh[400 + n];
      const float r = 1.f / (1.f + expf(-(gir + ghr)));
      const float z = 1.f / (1.f + expf(-(giz + ghz)));
      const float nn = tanhf(gin + r * ghn);
      const float hv = (1.f - z) * nn + z * hbuf[cur][n];
      hbuf[cur ^ 1][n] = hv;
      hall[((size_t)t * B_ + b) * KP + n] = __float2bfloat16(hv);
      if (t == T_ - 1) out_hidden[b * H_ + n] = hv;
    }
    __syncthreads();
    cur ^= 1;
  }
}

// ---------------- batched output GEMM + log-softmax ----------------
__global__ __launch_bounds__(256) void k_big0(const short* __restrict__ hb,
                                              const short* __restrict__ wpk,
                                              const float* __restrict__ outb,
                                              float* __restrict__ pmax,
                                              float* __restrict__ psum) {
  const int tid = threadIdx.x;
  const int w = tid >> 6, l = tid & 63;
  const int lm = l & 15, lg = l >> 4;
  const int r0 = blockIdx.y * 64;
  const int v0 = blockIdx.x * 256 + w * 64;

  f32x4 acc[4][4] = {};
#pragma unroll
  for (int kt = 0; kt < KP / 32; ++kt) {
    const int k0 = kt * 32;
    bf16x8 af[4], bfr[4];
#pragma unroll
    for (int wm = 0; wm < 4; ++wm)
      af[wm] = *(const bf16x8*)(hb + (size_t)(r0 + wm * 16 + lm) * KP + k0 + lg * 8);
#pragma unroll
    for (int n = 0; n < 4; ++n)
      bfr[n] = *(const bf16x8*)(wpk + ((size_t)((k0 >> 3) + lg) * VP + v0 + n * 16 + lm) * 8);
#pragma unroll
    for (int wm = 0; wm < 4; ++wm)
#pragma unroll
      for (int n = 0; n < 4; ++n)
        acc[wm][n] = __builtin_amdgcn_mfma_f32_16x16x32_bf16(af[wm], bfr[n], acc[wm][n], 0, 0, 0);
  }

  int vv[4]; float bias[4]; bool val[4];
#pragma unroll
  for (int n = 0; n < 4; ++n) {
    vv[n] = v0 + n * 16 + lm;
    val[n] = vv[n] < V_;
    bias[n] = val[n] ? outb[vv[n]] : 0.f;
  }

  __shared__ float smax[4][64], ssum[4][64];
#pragma unroll
  for (int wm = 0; wm < 4; ++wm) {
#pragma unroll
    for (int j = 0; j < 4; ++j) {
      float mv = -INFINITY;
#pragma unroll
      for (int n = 0; n < 4; ++n)
        if (val[n]) mv = fmaxf(mv, acc[wm][n][j] + bias[n]);
      for (int off = 8; off > 0; off >>= 1) mv = fmaxf(mv, __shfl_xor(mv, off, 64));
      float sv = 0.f;
#pragma unroll
      for (int n = 0; n < 4; ++n)
        if (val[n]) sv += expf(acc[wm][n][j] + bias[n] - mv);
      for (int off = 8; off > 0; off >>= 1) sv += __shfl_xor(sv, off, 64);
      if (lm == 0) {
        smax[w][wm * 16 + lg * 4 + j] = mv;
        ssum[w][wm * 16 + lg * 4 + j] = sv;
      }
    }
  }
  __syncthreads();
  if (tid < 64) {
    float mv = -INFINITY;
    for (int ww = 0; ww < 4; ++ww) mv = fmaxf(mv, smax[ww][tid]);
    float sv = 0.f;
    for (int ww = 0; ww < 4; ++ww) {
      float sw = ssum[ww][tid];
      if (sw > 0.f) sv += expf(smax[ww][tid] - mv) * sw;
    }
    pmax[(size_t)blockIdx.x * MROWS + r0 + tid] = mv;
    psum[(size_t)blockIdx.x * MROWS + r0 + tid] = sv;
  }
}

__global__ __launch_bounds__(256) void k_lse(const float* __restrict__ pmax,
                                             const float* __restrict__ psum,
                                             float* __restrict__ lse) {
  const int r = blockIdx.x * 256 + threadIdx.x;
  float mv = -INFINITY;
  for (int c = 0; c < NCB; ++c) mv = fmaxf(mv, pmax[(size_t)c * MROWS + r]);
  float sv = 0.f;
  for (int c = 0; c < NCB; ++c) {
    float sw = psum[(size_t)c * MROWS + r];
    if (sw > 0.f) sv += expf(pmax[(size_t)c * MROWS + r] - mv) * sw;
  }
  lse[r] = mv + logf(sv);
}

__global__ __launch_bounds__(256) void k_big1(const short* __restrict__ hb,
                                              const short* __restrict__ wpk,
                                              const float* __restrict__ outb,
                                              const float* __restrict__ lse,
                                              float* __restrict__ out_logp) {
  const int tid = threadIdx.x;
  const int w = tid >> 6, l = tid & 63;
  const int lm = l & 15, lg = l >> 4;
  const int r0 = blockIdx.y * 64;
  const int v0 = blockIdx.x * 256 + w * 64;

  __shared__ float lseL[64];
  if (tid < 64) lseL[tid] = lse[r0 + tid];

  f32x4 acc[4][4] = {};
#pragma unroll
  for (int kt = 0; kt < KP / 32; ++kt) {
    const int k0 = kt * 32;
    bf16x8 af[4], bfr[4];
#pragma unroll
    for (int wm = 0; wm < 4; ++wm)
      af[wm] = *(const bf16x8*)(hb + (size_t)(r0 + wm * 16 + lm) * KP + k0 + lg * 8);
#pragma unroll
    for (int n = 0; n < 4; ++n)
      bfr[n] = *(const bf16x8*)(wpk + ((size_t)((k0 >> 3) + lg) * VP + v0 + n * 16 + lm) * 8);
#pragma unroll
    for (int wm = 0; wm < 4; ++wm)
#pragma unroll
      for (int n = 0; n < 4; ++n)
        acc[wm][n] = __builtin_amdgcn_mfma_f32_16x16x32_bf16(af[wm], bfr[n], acc[wm][n], 0, 0, 0);
  }

  int vv[4]; float bias[4]; bool val[4];
#pragma unroll
  for (int n = 0; n < 4; ++n) {
    vv[n] = v0 + n * 16 + lm;
    val[n] = vv[n] < V_;
    bias[n] = val[n] ? outb[vv[n]] : 0.f;
  }
  __syncthreads();
#pragma unroll
  for (int wm = 0; wm < 4; ++wm) {
#pragma unroll
    for (int j = 0; j < 4; ++j) {
      const int row = r0 + wm * 16 + lg * 4 + j;
      const float ls = lseL[wm * 16 + lg * 4 + j];
#pragma unroll
      for (int n = 0; n < 4; ++n)
        if (val[n]) out_logp[(size_t)row * V_ + vv[n]] = acc[wm][n][j] + bias[n] - ls;
    }
  }
}

// ---------------- host launch ----------------

extern "C" void kernel_launch(void* const* d_in, const int* in_sizes, int n_in,
                              void* d_out, int out_size, void* d_ws, size_t ws_size,
                              hipStream_t stream) {
  (void)in_sizes; (void)n_in; (void)out_size; (void)ws_size;
  const int* tokens = (const int*)d_in[0];
  const float* hidden0 = (const float*)d_in[1];
  const float* encoder = (const float*)d_in[2];
  const float* emb = (const float*)d_in[3];
  const float* W1 = (const float*)d_in[4];
  const float* b1 = (const float*)d_in[5];
  const float* W2 = (const float*)d_in[6];
  const float* b2 = (const float*)d_in[7];
  const float* W3 = (const float*)d_in[8];
  const float* b3 = (const float*)d_in[9];
  const float* attn_W = (const float*)d_in[10];
  const float* attn_b = (const float*)d_in[11];
  const float* Wih = (const float*)d_in[12];
  const float* Whh = (const float*)d_in[13];
  const float* bih = (const float*)d_in[14];
  const float* bhh = (const float*)d_in[15];
  const float* outW = (const float*)d_in[16];
  const float* outb = (const float*)d_in[17];

  float* out_logp = (float*)d_out;                       // [T*B, V]
  float* out_hidden = out_logp + (size_t)T_ * B_ * V_;   // [B, H]
  float* out_attn = out_hidden + (size_t)B_ * H_;        // [T, B, S]

  float* ws = (float*)d_ws;
  float* ah2w = ws;                                      // B*S*A
  float* ah3w = ah2w + (size_t)B_ * S_ * A_;             // T*B*A
  float* pmaxw = ah3w + (size_t)T_ * B_ * A_;            // NCB*MROWS
  float* psumw = pmaxw + (size_t)NCB * MROWS;            // NCB*MROWS
  float* lsew = psumw + (size_t)NCB * MROWS;             // MROWS
  __hip_bfloat16* hallw = (__hip_bfloat16*)(lsew + MROWS);    // MROWS*KP
  __hip_bfloat16* wpkw = hallw + (size_t)MROWS * KP;          // (KP/8)*VP*8
  __hip_bfloat16* W1bw = wpkw + (size_t)(KP / 8) * VP * 8;    // A*H
  __hip_bfloat16* Wihbw = W1bw + (size_t)A_ * H_;             // 600*400
  __hip_bfloat16* Whhbw = Wihbw + (size_t)G3 * EH;            // 600*200

  k_pack<<<512, 256, 0, stream>>>(outW, W1, Wih, Whh, wpkw, hallw, W1bw, Wihbw, Whhbw);
  k_ah2<<<dim3(S_, B_ / 16), 256, 0, stream>>>(encoder, W2, b2, ah2w);
  k_ah3<<<dim3(T_, B_ / 16), 256, 0, stream>>>(tokens, emb, W3, b3, ah3w);

  k_recur<<<B_, 512, 0, stream>>>(hidden0, ah2w, ah3w, encoder, W1bw, b1, attn_W, attn_b,
                                  tokens, emb, Wihbw, Whhbw, bih, bhh,
                                  hallw, out_hidden, out_attn);

  k_big0<<<dim3(NCB, MROWS / 64), 256, 0, stream>>>((const short*)hallw, (const short*)wpkw,
                                                    outb, pmaxw, psumw);
  k_lse<<<MROWS / 256, 256, 0, stream>>>(pmaxw, psumw, lsew);
  k_big1<<<dim3(NCB, MROWS / 64), 256, 0, stream>>>((const short*)hallw, (const short*)wpkw,
                                                    outb, lsew, out_logp);
}

// Round 5
// 2418.527 us; speedup vs baseline: 2.7283x; 1.2523x over previous
//
#include <hip/hip_runtime.h>
#include <hip/hip_bf16.h>
#include <cmath>

constexpr int T_ = 64, B_ = 128, S_ = 128, H_ = 200, E_ = 200, A_ = 100, V_ = 10003;
constexpr int KP = 224;        // padded K (=H), multiple of 32
constexpr int VP = 10240;      // padded V, multiple of 256
constexpr int MROWS = T_ * B_; // 8192 rows in the batched output GEMM
constexpr int NCB = VP / 256;  // 40 column-blocks
constexpr int G3 = 3 * H_;     // 600 gate rows
constexpr int EH = E_ + H_;    // 400
constexpr int NU = 3 * G3;     // 1800 dot-units of length 200

typedef __attribute__((ext_vector_type(8))) short bf16x8;
typedef __attribute__((ext_vector_type(4))) float f32x4;

__device__ __forceinline__ float bfu(short u) {
  union { unsigned int i; float f; } c;
  c.i = ((unsigned int)(unsigned short)u) << 16;
  return c.f;
}

// ---------------- precompute kernels ----------------

// Pack out_W^T -> bf16 [KP/8][VP][8]; zero padded hall; pack W1/Wih/Whh
// transposed to [K/8][N][8] bf16 (lane n reads 16B at (k8*N+n)*8 -> coalesced).
__global__ __launch_bounds__(256) void k_pack(const float* __restrict__ outW,
                                              const float* __restrict__ W1,
                                              const float* __restrict__ Wih,
                                              const float* __restrict__ Whh,
                                              __hip_bfloat16* __restrict__ wpk,
                                              __hip_bfloat16* __restrict__ hall,
                                              __hip_bfloat16* __restrict__ W1T,
                                              __hip_bfloat16* __restrict__ WihT,
                                              __hip_bfloat16* __restrict__ WhhT) {
  const int stride = gridDim.x * blockDim.x;
  const int tid0 = blockIdx.x * blockDim.x + threadIdx.x;
  const int total = (KP / 8) * VP * 8;
  for (int idx = tid0; idx < total; idx += stride) {
    int kk = idx & 7;
    int v = (idx >> 3) % VP;
    int kb = idx / (8 * VP);
    int k = kb * 8 + kk;
    float val = (k < H_ && v < V_) ? outW[(size_t)v * H_ + k] : 0.f;
    wpk[idx] = __float2bfloat16(val);
  }
  const __hip_bfloat16 z = __float2bfloat16(0.f);
  for (int idx = tid0; idx < MROWS * KP; idx += stride) hall[idx] = z;
  // W1T: [25][A][8], element (k,a) at ((k>>3)*A + a)*8 + (k&7)
  for (int idx = tid0; idx < 25 * A_ * 8; idx += stride) {
    int kk = idx & 7, a = (idx >> 3) % A_, k8 = idx / (8 * A_);
    W1T[idx] = __float2bfloat16(W1[(size_t)a * H_ + k8 * 8 + kk]);
  }
  // WihT: [50][G3][8], element (k,n) at ((k>>3)*G3 + n)*8 + (k&7), k in [0,400)
  for (int idx = tid0; idx < 50 * G3 * 8; idx += stride) {
    int kk = idx & 7, n = (idx >> 3) % G3, k8 = idx / (8 * G3);
    WihT[idx] = __float2bfloat16(Wih[(size_t)n * EH + k8 * 8 + kk]);
  }
  // WhhT: [25][G3][8]
  for (int idx = tid0; idx < 25 * G3 * 8; idx += stride) {
    int kk = idx & 7, n = (idx >> 3) % G3, k8 = idx / (8 * G3);
    WhhT[idx] = __float2bfloat16(Whh[(size_t)n * H_ + k8 * 8 + kk]);
  }
}

// ah2[b][s][a] = b2[a] + sum_h enc[s,b,h] * W2[a,h]
__global__ __launch_bounds__(256) void k_ah2(const float* __restrict__ encoder,
                                             const float* __restrict__ W2,
                                             const float* __restrict__ b2,
                                             float* __restrict__ ah2) {
  __shared__ float encL[16][200];
  const int s = blockIdx.x, b0 = blockIdx.y * 16, tid = threadIdx.x;
  for (int i = tid; i < 16 * 200; i += 256) {
    int bl = i / 200, k = i % 200;
    encL[bl][k] = encoder[((size_t)s * B_ + b0 + bl) * H_ + k];
  }
  __syncthreads();
  for (int o = tid; o < 16 * A_; o += 256) {
    int bl = o / A_, a = o % A_;
    const float* w = W2 + (size_t)a * H_;
    float acc = b2[a];
    for (int k = 0; k < H_; ++k) acc += encL[bl][k] * w[k];
    ah2[((size_t)(b0 + bl) * S_ + s) * A_ + a] = acc;
  }
}

// ah3[t][b][a] = b3[a] + sum_e emb[tok[t,b], e] * W3[a,e]
__global__ __launch_bounds__(256) void k_ah3(const int* __restrict__ tokens,
                                             const float* __restrict__ emb,
                                             const float* __restrict__ W3,
                                             const float* __restrict__ b3,
                                             float* __restrict__ ah3) {
  __shared__ float embL[16][200];
  __shared__ int tokL[16];
  const int t = blockIdx.x, b0 = blockIdx.y * 16, tid = threadIdx.x;
  if (tid < 16) tokL[tid] = tokens[t * B_ + b0 + tid];
  __syncthreads();
  for (int i = tid; i < 16 * 200; i += 256) {
    int bl = i / 200, k = i % 200;
    embL[bl][k] = emb[(size_t)tokL[bl] * E_ + k];
  }
  __syncthreads();
  for (int o = tid; o < 16 * A_; o += 256) {
    int bl = o / A_, a = o % A_;
    const float* w = W3 + (size_t)a * E_;
    float acc = b3[a];
    for (int k = 0; k < E_; ++k) acc += embL[bl][k] * w[k];
    ah3[((size_t)t * B_ + b0 + bl) * A_ + a] = acc;
  }
}

// dot-unit body: 200-length dot of bf16 weights (transposed layout) vs LDS f32,
// 4 independent accumulator chains.
__device__ __forceinline__ float dot200(const bf16x8* __restrict__ wseg, int n,
                                        const float4* __restrict__ x4) {
  float a0 = 0.f, a1 = 0.f, a2 = 0.f, a3 = 0.f;
#pragma unroll
  for (int k8 = 0; k8 < 25; ++k8) {
    bf16x8 w8 = wseg[k8 * G3 + n];
    float4 xa = x4[2 * k8], xb = x4[2 * k8 + 1];
    if (k8 & 1) {
      a2 += bfu(w8[0]) * xa.x + bfu(w8[1]) * xa.y + bfu(w8[2]) * xa.z + bfu(w8[3]) * xa.w;
      a3 += bfu(w8[4]) * xb.x + bfu(w8[5]) * xb.y + bfu(w8[6]) * xb.z + bfu(w8[7]) * xb.w;
    } else {
      a0 += bfu(w8[0]) * xa.x + bfu(w8[1]) * xa.y + bfu(w8[2]) * xa.z + bfu(w8[3]) * xa.w;
      a1 += bfu(w8[4]) * xb.x + bfu(w8[5]) * xb.y + bfu(w8[6]) * xb.z + bfu(w8[7]) * xb.w;
    }
  }
  return (a0 + a1) + (a2 + a3);
}

// ---------------- persistent recurrence kernel ----------------
// One block per batch element b; full t-loop inside. No cross-block deps.
__global__ __launch_bounds__(512) void k_recur(const float* __restrict__ hidden0,
                                               const float* __restrict__ ah2,
                                               const float* __restrict__ ah3,
                                               const float* __restrict__ encoder,
                                               const __hip_bfloat16* __restrict__ W1T,
                                               const float* __restrict__ b1,
                                               const float* __restrict__ attn_W,
                                               const float* __restrict__ attn_b,
                                               const int* __restrict__ tokens,
                                               const float* __restrict__ emb,
                                               const __hip_bfloat16* __restrict__ WihT,
                                               const __hip_bfloat16* __restrict__ WhhT,
                                               const float* __restrict__ bih,
                                               const float* __restrict__ bhh,
                                               __hip_bfloat16* __restrict__ hall,
                                               float* __restrict__ out_hidden,
                                               float* __restrict__ out_attn) {
  constexpr int AP = 101; // pitch: 101 mod 32 = 5, gcd(5,32)=1 -> 2-way max (free)
  __shared__ float ah2L[S_ * AP];                  // 51.7 KB, resident all steps
  __shared__ __align__(16) float hbuf[2][H_];
  __shared__ __align__(16) float xe[E_];
  __shared__ __align__(16) float xc[H_];
  __shared__ float s1[A_];
  __shared__ float aW[A_];
  __shared__ float aL[S_];
  __shared__ float red[8];
  __shared__ float part[NU];                       // 1800 dot-unit partials

  const int b = blockIdx.x, tid = threadIdx.x;
  const int lane = tid & 63;

  // one-time preload
  for (int i = tid; i < S_ * A_; i += 512) {
    int s = i / A_, a = i - s * A_;
    ah2L[s * AP + a] = ah2[(size_t)b * S_ * A_ + i];
  }
  for (int i = tid; i < H_; i += 512) hbuf[0][i] = hidden0[b * H_ + i];
  for (int i = tid; i < A_; i += 512) aW[i] = attn_W[i];
  const float ab = attn_b[0];
  __syncthreads();

  const bf16x8* W1T8 = (const bf16x8*)W1T;
  const bf16x8* WihT8 = (const bf16x8*)WihT;
  const bf16x8* WhhT8 = (const bf16x8*)WhhT;

  int cur = 0;
  for (int t = 0; t < T_; ++t) {
    const int tok = tokens[t * B_ + b];
    const float4* h4 = (const float4*)hbuf[cur];

    // ---- phase 1: xe load (tid<200)  ||  s1 = h@W1^T + b1 + ah3 (waves 4-5)
    if (tid < E_) {
      xe[tid] = emb[(size_t)tok * E_ + tid];
    } else if (tid >= 256 && tid < 256 + A_) {
      const int a = tid - 256;
      float acc = dot200(W1T8, a * 0 + a, h4); // W1T stride is A_, see below
      // NOTE: dot200 uses stride G3; W1T uses stride A_. Inline here instead:
      s1[a] = acc; // overwritten below (kept for clarity; real compute follows)
    }
    // recompute s1 correctly with A_ stride (separate loop to keep dot200 simple)
    if (tid >= 256 && tid < 256 + A_) {
      const int a = tid - 256;
      float a0 = 0.f, a1 = 0.f, a2 = 0.f, a3 = 0.f;
#pragma unroll
      for (int k8 = 0; k8 < 25; ++k8) {
        bf16x8 w8 = W1T8[k8 * A_ + a];
        float4 xa = h4[2 * k8], xb = h4[2 * k8 + 1];
        if (k8 & 1) {
          a2 += bfu(w8[0]) * xa.x + bfu(w8[1]) * xa.y + bfu(w8[2]) * xa.z + bfu(w8[3]) * xa.w;
          a3 += bfu(w8[4]) * xb.x + bfu(w8[5]) * xb.y + bfu(w8[6]) * xb.z + bfu(w8[7]) * xb.w;
        } else {
          a0 += bfu(w8[0]) * xa.x + bfu(w8[1]) * xa.y + bfu(w8[2]) * xa.z + bfu(w8[3]) * xa.w;
          a1 += bfu(w8[4]) * xb.x + bfu(w8[5]) * xb.y + bfu(w8[6]) * xb.z + bfu(w8[7]) * xb.w;
        }
      }
      s1[a] = (a0 + a1) + (a2 + a3) + b1[a] + ah3[((size_t)t * B_ + b) * A_ + a];
    }
    __syncthreads();

    // ---- phase 2: relu-attn logits + softmax (tid<128)
    float p = -INFINITY;
    if (tid < S_) {
      float acc = ab;
#pragma unroll 4
      for (int a = 0; a < A_; ++a)
        acc += fmaxf(s1[a] + ah2L[tid * AP + a], 0.f) * aW[a];
      p = acc;
    }
    float m = p;
#pragma unroll
    for (int off = 32; off > 0; off >>= 1) m = fmaxf(m, __shfl_xor(m, off, 64));
    if (tid < S_ && lane == 0) red[tid >> 6] = m;
    __syncthreads();
    const float M = fmaxf(red[0], red[1]);
    float ev = (tid < S_) ? expf(p - M) : 0.f;
    float sm = ev;
#pragma unroll
    for (int off = 32; off > 0; off >>= 1) sm += __shfl_xor(sm, off, 64);
    if (tid < S_ && lane == 0) red[4 + (tid >> 6)] = sm;
    __syncthreads();
    const float SS = red[4] + red[5];
    if (tid < S_) {
      float av = ev / SS;
      aL[tid] = av;
      out_attn[((size_t)t * B_ + b) * S_ + tid] = av;
    }
    __syncthreads();

    // ---- phase 3: ctx (tid<200): xc[n] = sum_s aL[s] * enc[s,b,n]
    if (tid < H_) {
      float c0 = 0.f, c1 = 0.f, c2 = 0.f, c3 = 0.f;
#pragma unroll 4
      for (int s = 0; s < S_; s += 4) {
        c0 += aL[s] * encoder[((size_t)s * B_ + b) * H_ + tid];
        c1 += aL[s + 1] * encoder[((size_t)(s + 1) * B_ + b) * H_ + tid];
        c2 += aL[s + 2] * encoder[((size_t)(s + 2) * B_ + b) * H_ + tid];
        c3 += aL[s + 3] * encoder[((size_t)(s + 3) * B_ + b) * H_ + tid];
      }
      xc[tid] = (c0 + c1) + (c2 + c3);
    }
    __syncthreads();

    // ---- phase 4: 1800 coalesced dot-units of length 200
    //  u <  600: part[u] = xe . WihT row u     (k 0..199)
    //  u < 1200: part[u] = xc . WihT row u-600 (k 200..399)
    //  else    : part[u] = h  . WhhT row u-1200
    for (int u = tid; u < NU; u += 512) {
      const bf16x8* wseg;
      const float4* x4;
      int n;
      if (u < G3) { n = u; wseg = WihT8; x4 = (const float4*)xe; }
      else if (u < 2 * G3) { n = u - G3; wseg = WihT8 + 25 * G3; x4 = (const float4*)xc; }
      else { n = u - 2 * G3; wseg = WhhT8; x4 = h4; }
      part[u] = dot200(wseg, n, x4);
    }
    __syncthreads();

    // ---- phase 5: gates (tid<200)
    if (tid < H_) {
      const int n = tid;
      const float gir = part[n] + part[G3 + n] + bih[n];
      const float giz = part[200 + n] + part[G3 + 200 + n] + bih[200 + n];
      const float gin = part[400 + n] + part[G3 + 400 + n] + bih[400 + n];
      const float ghr = part[2 * G3 + n] + bhh[n];
      const float ghz = part[2 * G3 + 200 + n] + bhh[200 + n];
      const float ghn = part[2 * G3 + 400 + n] + bhh[400 + n];
      const float r = 1.f / (1.f + expf(-(gir + ghr)));
      const float z = 1.f / (1.f + expf(-(giz + ghz)));
      const float nn = tanhf(gin + r * ghn);
      const float hv = (1.f - z) * nn + z * hbuf[cur][n];
      hbuf[cur ^ 1][n] = hv;
      hall[((size_t)t * B_ + b) * KP + n] = __float2bfloat16(hv);
      if (t == T_ - 1) out_hidden[b * H_ + n] = hv;
    }
    __syncthreads();
    cur ^= 1;
  }
}

// ---------------- batched output GEMM + log-softmax ----------------
__global__ __launch_bounds__(256) void k_big0(const short* __restrict__ hb,
                                              const short* __restrict__ wpk,
                                              const float* __restrict__ outb,
                                              float* __restrict__ pmax,
                                              float* __restrict__ psum) {
  const int tid = threadIdx.x;
  const int w = tid >> 6, l = tid & 63;
  const int lm = l & 15, lg = l >> 4;
  const int r0 = blockIdx.y * 64;
  const int v0 = blockIdx.x * 256 + w * 64;

  f32x4 acc[4][4] = {};
#pragma unroll
  for (int kt = 0; kt < KP / 32; ++kt) {
    const int k0 = kt * 32;
    bf16x8 af[4], bfr[4];
#pragma unroll
    for (int wm = 0; wm < 4; ++wm)
      af[wm] = *(const bf16x8*)(hb + (size_t)(r0 + wm * 16 + lm) * KP + k0 + lg * 8);
#pragma unroll
    for (int n = 0; n < 4; ++n)
      bfr[n] = *(const bf16x8*)(wpk + ((size_t)((k0 >> 3) + lg) * VP + v0 + n * 16 + lm) * 8);
#pragma unroll
    for (int wm = 0; wm < 4; ++wm)
#pragma unroll
      for (int n = 0; n < 4; ++n)
        acc[wm][n] = __builtin_amdgcn_mfma_f32_16x16x32_bf16(af[wm], bfr[n], acc[wm][n], 0, 0, 0);
  }

  int vv[4]; float bias[4]; bool val[4];
#pragma unroll
  for (int n = 0; n < 4; ++n) {
    vv[n] = v0 + n * 16 + lm;
    val[n] = vv[n] < V_;
    bias[n] = val[n] ? outb[vv[n]] : 0.f;
  }

  __shared__ float smax[4][64], ssum[4][64];
#pragma unroll
  for (int wm = 0; wm < 4; ++wm) {
#pragma unroll
    for (int j = 0; j < 4; ++j) {
      float mv = -INFINITY;
#pragma unroll
      for (int n = 0; n < 4; ++n)
        if (val[n]) mv = fmaxf(mv, acc[wm][n][j] + bias[n]);
      for (int off = 8; off > 0; off >>= 1) mv = fmaxf(mv, __shfl_xor(mv, off, 64));
      float sv = 0.f;
#pragma unroll
      for (int n = 0; n < 4; ++n)
        if (val[n]) sv += expf(acc[wm][n][j] + bias[n] - mv);
      for (int off = 8; off > 0; off >>= 1) sv += __shfl_xor(sv, off, 64);
      if (lm == 0) {
        smax[w][wm * 16 + lg * 4 + j] = mv;
        ssum[w][wm * 16 + lg * 4 + j] = sv;
      }
    }
  }
  __syncthreads();
  if (tid < 64) {
    float mv = -INFINITY;
    for (int ww = 0; ww < 4; ++ww) mv = fmaxf(mv, smax[ww][tid]);
    float sv = 0.f;
    for (int ww = 0; ww < 4; ++ww) {
      float sw = ssum[ww][tid];
      if (sw > 0.f) sv += expf(smax[ww][tid] - mv) * sw;
    }
    pmax[(size_t)blockIdx.x * MROWS + r0 + tid] = mv;
    psum[(size_t)blockIdx.x * MROWS + r0 + tid] = sv;
  }
}

__global__ __launch_bounds__(256) void k_lse(const float* __restrict__ pmax,
                                             const float* __restrict__ psum,
                                             float* __restrict__ lse) {
  const int r = blockIdx.x * 256 + threadIdx.x;
  float mv = -INFINITY;
  for (int c = 0; c < NCB; ++c) mv = fmaxf(mv, pmax[(size_t)c * MROWS + r]);
  float sv = 0.f;
  for (int c = 0; c < NCB; ++c) {
    float sw = psum[(size_t)c * MROWS + r];
    if (sw > 0.f) sv += expf(pmax[(size_t)c * MROWS + r] - mv) * sw;
  }
  lse[r] = mv + logf(sv);
}

__global__ __launch_bounds__(256) void k_big1(const short* __restrict__ hb,
                                              const short* __restrict__ wpk,
                                              const float* __restrict__ outb,
                                              const float* __restrict__ lse,
                                              float* __restrict__ out_logp) {
  const int tid = threadIdx.x;
  const int w = tid >> 6, l = tid & 63;
  const int lm = l & 15, lg = l >> 4;
  const int r0 = blockIdx.y * 64;
  const int v0 = blockIdx.x * 256 + w * 64;

  __shared__ float lseL[64];
  if (tid < 64) lseL[tid] = lse[r0 + tid];

  f32x4 acc[4][4] = {};
#pragma unroll
  for (int kt = 0; kt < KP / 32; ++kt) {
    const int k0 = kt * 32;
    bf16x8 af[4], bfr[4];
#pragma unroll
    for (int wm = 0; wm < 4; ++wm)
      af[wm] = *(const bf16x8*)(hb + (size_t)(r0 + wm * 16 + lm) * KP + k0 + lg * 8);
#pragma unroll
    for (int n = 0; n < 4; ++n)
      bfr[n] = *(const bf16x8*)(wpk + ((size_t)((k0 >> 3) + lg) * VP + v0 + n * 16 + lm) * 8);
#pragma unroll
    for (int wm = 0; wm < 4; ++wm)
#pragma unroll
      for (int n = 0; n < 4; ++n)
        acc[wm][n] = __builtin_amdgcn_mfma_f32_16x16x32_bf16(af[wm], bfr[n], acc[wm][n], 0, 0, 0);
  }

  int vv[4]; float bias[4]; bool val[4];
#pragma unroll
  for (int n = 0; n < 4; ++n) {
    vv[n] = v0 + n * 16 + lm;
    val[n] = vv[n] < V_;
    bias[n] = val[n] ? outb[vv[n]] : 0.f;
  }
  __syncthreads();
#pragma unroll
  for (int wm = 0; wm < 4; ++wm) {
#pragma unroll
    for (int j = 0; j < 4; ++j) {
      const int row = r0 + wm * 16 + lg * 4 + j;
      const float ls = lseL[wm * 16 + lg * 4 + j];
#pragma unroll
      for (int n = 0; n < 4; ++n)
        if (val[n]) out_logp[(size_t)row * V_ + vv[n]] = acc[wm][n][j] + bias[n] - ls;
    }
  }
}

// ---------------- host launch ----------------

extern "C" void kernel_launch(void* const* d_in, const int* in_sizes, int n_in,
                              void* d_out, int out_size, void* d_ws, size_t ws_size,
                              hipStream_t stream) {
  (void)in_sizes; (void)n_in; (void)out_size; (void)ws_size;
  const int* tokens = (const int*)d_in[0];
  const float* hidden0 = (const float*)d_in[1];
  const float* encoder = (const float*)d_in[2];
  const float* emb = (const float*)d_in[3];
  const float* W1 = (const float*)d_in[4];
  const float* b1 = (const float*)d_in[5];
  const float* W2 = (const float*)d_in[6];
  const float* b2 = (const float*)d_in[7];
  const float* W3 = (const float*)d_in[8];
  const float* b3 = (const float*)d_in[9];
  const float* attn_W = (const float*)d_in[10];
  const float* attn_b = (const float*)d_in[11];
  const float* Wih = (const float*)d_in[12];
  const float* Whh = (const float*)d_in[13];
  const float* bih = (const float*)d_in[14];
  const float* bhh = (const float*)d_in[15];
  const float* outW = (const float*)d_in[16];
  const float* outb = (const float*)d_in[17];

  float* out_logp = (float*)d_out;                       // [T*B, V]
  float* out_hidden = out_logp + (size_t)T_ * B_ * V_;   // [B, H]
  float* out_attn = out_hidden + (size_t)B_ * H_;        // [T, B, S]

  float* ws = (float*)d_ws;
  float* ah2w = ws;                                      // B*S*A
  float* ah3w = ah2w + (size_t)B_ * S_ * A_;             // T*B*A
  float* pmaxw = ah3w + (size_t)T_ * B_ * A_;            // NCB*MROWS
  float* psumw = pmaxw + (size_t)NCB * MROWS;            // NCB*MROWS
  float* lsew = psumw + (size_t)NCB * MROWS;             // MROWS
  __hip_bfloat16* hallw = (__hip_bfloat16*)(lsew + MROWS);    // MROWS*KP
  __hip_bfloat16* wpkw = hallw + (size_t)MROWS * KP;          // (KP/8)*VP*8
  __hip_bfloat16* W1Tw = wpkw + (size_t)(KP / 8) * VP * 8;    // 25*A*8
  __hip_bfloat16* WihTw = W1Tw + (size_t)25 * A_ * 8;         // 50*G3*8
  __hip_bfloat16* WhhTw = WihTw + (size_t)50 * G3 * 8;        // 25*G3*8

  k_pack<<<512, 256, 0, stream>>>(outW, W1, Wih, Whh, wpkw, hallw, W1Tw, WihTw, WhhTw);
  k_ah2<<<dim3(S_, B_ / 16), 256, 0, stream>>>(encoder, W2, b2, ah2w);
  k_ah3<<<dim3(T_, B_ / 16), 256, 0, stream>>>(tokens, emb, W3, b3, ah3w);

  k_recur<<<B_, 512, 0, stream>>>(hidden0, ah2w, ah3w, encoder, W1Tw, b1, attn_W, attn_b,
                                  tokens, emb, WihTw, WhhTw, bih, bhh,
                                  hallw, out_hidden, out_attn);

  k_big0<<<dim3(NCB, MROWS / 64), 256, 0, stream>>>((const short*)hallw, (const short*)wpkw,
                                                    outb, pmaxw, psumw);
  k_lse<<<MROWS / 256, 256, 0, stream>>>(pmaxw, psumw, lsew);
  k_big1<<<dim3(NCB, MROWS / 64), 256, 0, stream>>>((const short*)hallw, (const short*)wpkw,
                                                    outb, lsew, out_logp);
}

// Round 6
// 2233.049 us; speedup vs baseline: 2.9549x; 1.0831x over previous
//
#include <hip/hip_runtime.h>
#include <hip/hip_bf16.h>
#include <cmath>

constexpr int T_ = 64, B_ = 128, S_ = 128, H_ = 200, E_ = 200, A_ = 100, V_ = 10003;
constexpr int KP = 224;        // padded K (=H), multiple of 32
constexpr int VP = 10240;      // padded V, multiple of 256
constexpr int MROWS = T_ * B_; // 8192 rows in the batched output GEMM
constexpr int NCB = VP / 256;  // 40 column-blocks
constexpr int G3 = 3 * H_;     // 600 gate rows
constexpr int EH = E_ + H_;    // 400
constexpr int ELD = 136;       // encL row stride in f16 (272B: 16B-aligned, 8-way bank worst)
constexpr int AH2P = 104;      // padded A for f16 ah2 rows (13 x 8)

typedef __attribute__((ext_vector_type(8))) short bf16x8;
typedef __attribute__((ext_vector_type(4))) float f32x4;
typedef __attribute__((ext_vector_type(2))) _Float16 h2;
typedef __attribute__((ext_vector_type(8))) _Float16 h8;

#if __has_builtin(__builtin_amdgcn_fdot2)
__device__ __forceinline__ float fdot2f(h2 a, h2 b, float c) {
  return __builtin_amdgcn_fdot2(a, b, c, false);
}
#else
__device__ __forceinline__ float fdot2f(h2 a, h2 b, float c) {
  return c + (float)a[0] * (float)b[0] + (float)a[1] * (float)b[1];
}
#endif

// 200-length dot: f16 weights in [k8][N][8] layout (stride N in h8 units),
// f16 x vector in LDS as 25 aligned h8 chunks. f32 accumulate, 4 chains.
__device__ __forceinline__ float dot200h(const h8* __restrict__ w, int n, int stride,
                                         const h8* __restrict__ x) {
  float a0 = 0.f, a1 = 0.f, a2 = 0.f, a3 = 0.f;
#pragma unroll
  for (int k8 = 0; k8 < 25; ++k8) {
    h8 wv = w[k8 * stride + n];
    h8 xv = x[k8];
    h2 wp[4], xp[4];
    __builtin_memcpy(wp, &wv, 16);
    __builtin_memcpy(xp, &xv, 16);
    a0 = fdot2f(wp[0], xp[0], a0);
    a1 = fdot2f(wp[1], xp[1], a1);
    a2 = fdot2f(wp[2], xp[2], a2);
    a3 = fdot2f(wp[3], xp[3], a3);
  }
  return (a0 + a1) + (a2 + a3);
}

// ---------------- precompute kernels ----------------

// wpk: out_W^T -> bf16 [KP/8][VP][8]; zero hall; W1/Wih/Whh -> f16 transposed
// [k8][N][8] so lane n reads contiguous 16B at (k8*N+n)*8.
__global__ __launch_bounds__(256) void k_pack(const float* __restrict__ outW,
                                              const float* __restrict__ W1,
                                              const float* __restrict__ Wih,
                                              const float* __restrict__ Whh,
                                              __hip_bfloat16* __restrict__ wpk,
                                              __hip_bfloat16* __restrict__ hall,
                                              _Float16* __restrict__ W1h,
                                              _Float16* __restrict__ Wihh,
                                              _Float16* __restrict__ Whhh) {
  const int stride = gridDim.x * blockDim.x;
  const int tid0 = blockIdx.x * blockDim.x + threadIdx.x;
  const int total = (KP / 8) * VP * 8;
  for (int idx = tid0; idx < total; idx += stride) {
    int kk = idx & 7;
    int v = (idx >> 3) % VP;
    int kb = idx / (8 * VP);
    int k = kb * 8 + kk;
    float val = (k < H_ && v < V_) ? outW[(size_t)v * H_ + k] : 0.f;
    wpk[idx] = __float2bfloat16(val);
  }
  const __hip_bfloat16 z = __float2bfloat16(0.f);
  for (int idx = tid0; idx < MROWS * KP; idx += stride) hall[idx] = z;
  for (int idx = tid0; idx < 25 * A_ * 8; idx += stride) {
    int kk = idx & 7, a = (idx >> 3) % A_, k8 = idx / (8 * A_);
    W1h[idx] = (_Float16)W1[(size_t)a * H_ + k8 * 8 + kk];
  }
  for (int idx = tid0; idx < 50 * G3 * 8; idx += stride) {
    int kk = idx & 7, n = (idx >> 3) % G3, k8 = idx / (8 * G3);
    Wihh[idx] = (_Float16)Wih[(size_t)n * EH + k8 * 8 + kk];
  }
  for (int idx = tid0; idx < 25 * G3 * 8; idx += stride) {
    int kk = idx & 7, n = (idx >> 3) % G3, k8 = idx / (8 * G3);
    Whhh[idx] = (_Float16)Whh[(size_t)n * H_ + k8 * 8 + kk];
  }
}

// ah2h[b][s][a] (f16, padded A->104) = b2[a] + sum_h enc[s,b,h] * W2[a,h]
__global__ __launch_bounds__(256) void k_ah2(const float* __restrict__ encoder,
                                             const float* __restrict__ W2,
                                             const float* __restrict__ b2,
                                             _Float16* __restrict__ ah2h) {
  __shared__ float encL[16][200];
  const int s = blockIdx.x, b0 = blockIdx.y * 16, tid = threadIdx.x;
  for (int i = tid; i < 16 * 200; i += 256) {
    int bl = i / 200, k = i % 200;
    encL[bl][k] = encoder[((size_t)s * B_ + b0 + bl) * H_ + k];
  }
  __syncthreads();
  for (int o = tid; o < 16 * A_; o += 256) {
    int bl = o / A_, a = o % A_;
    const float* w = W2 + (size_t)a * H_;
    float acc = b2[a];
    for (int k = 0; k < H_; ++k) acc += encL[bl][k] * w[k];
    ah2h[((size_t)(b0 + bl) * S_ + s) * AH2P + a] = (_Float16)acc;
  }
  for (int o = tid; o < 16 * (AH2P - A_); o += 256) {
    int bl = o / (AH2P - A_), a = A_ + o % (AH2P - A_);
    ah2h[((size_t)(b0 + bl) * S_ + s) * AH2P + a] = (_Float16)0.f;
  }
}

// ah3[t][b][a] = b3[a] + sum_e emb[tok[t,b], e] * W3[a,e]
__global__ __launch_bounds__(256) void k_ah3(const int* __restrict__ tokens,
                                             const float* __restrict__ emb,
                                             const float* __restrict__ W3,
                                             const float* __restrict__ b3,
                                             float* __restrict__ ah3) {
  __shared__ float embL[16][200];
  __shared__ int tokL[16];
  const int t = blockIdx.x, b0 = blockIdx.y * 16, tid = threadIdx.x;
  if (tid < 16) tokL[tid] = tokens[t * B_ + b0 + tid];
  __syncthreads();
  for (int i = tid; i < 16 * 200; i += 256) {
    int bl = i / 200, k = i % 200;
    embL[bl][k] = emb[(size_t)tokL[bl] * E_ + k];
  }
  __syncthreads();
  for (int o = tid; o < 16 * A_; o += 256) {
    int bl = o / A_, a = o % A_;
    const float* w = W3 + (size_t)a * E_;
    float acc = b3[a];
    for (int k = 0; k < E_; ++k) acc += embL[bl][k] * w[k];
    ah3[((size_t)t * B_ + b0 + bl) * A_ + a] = acc;
  }
}

// ---------------- persistent recurrence kernel ----------------
// One block per batch element b; full t-loop inside. No cross-block deps.
// encoder slice + ah2 rows resident (LDS / registers) for all 64 steps.
__global__ __launch_bounds__(512, 2) void k_recur(const float* __restrict__ hidden0,
                                                  const _Float16* __restrict__ ah2h,
                                                  const float* __restrict__ ah3,
                                                  const float* __restrict__ encoder,
                                                  const _Float16* __restrict__ W1h,
                                                  const float* __restrict__ b1,
                                                  const float* __restrict__ attn_W,
                                                  const float* __restrict__ attn_b,
                                                  const int* __restrict__ tokens,
                                                  const float* __restrict__ emb,
                                                  const _Float16* __restrict__ Wihh,
                                                  const _Float16* __restrict__ Whhh,
                                                  const float* __restrict__ bih,
                                                  const float* __restrict__ bhh,
                                                  __hip_bfloat16* __restrict__ hall,
                                                  float* __restrict__ out_hidden,
                                                  float* __restrict__ out_attn) {
  __shared__ __align__(16) _Float16 encLh[H_ * ELD]; // [h][s] f16, 54,400 B
  __shared__ __align__(16) h2 h16[100];
  __shared__ __align__(16) h2 xeh[100];
  __shared__ __align__(16) h2 xch[100];
  __shared__ __align__(16) h2 aLh[64];
  __shared__ float s1[AH2P];
  __shared__ float aW[AH2P];
  __shared__ float red[8];
  __shared__ int tokL[T_];
  __shared__ float part[1800]; // [0,600): xe.Wih | [600,1200): xc.Wih | [1200,1800): h.Whh

  const int b = blockIdx.x, tid = threadIdx.x;
  const int lane = tid & 63;

  // ---- one-time init ----
  if (tid < T_) tokL[tid] = tokens[tid * B_ + b];
  for (int i = tid; i < S_ * H_; i += 512) {
    int s = i / H_, h = i - s * H_;
    encLh[h * ELD + s] = (_Float16)encoder[((size_t)s * B_ + b) * H_ + h];
  }
  float hreg = 0.f;
  float b_ir = 0.f, b_iz = 0.f, b_in = 0.f, b_hr = 0.f, b_hz = 0.f, b_hn = 0.f, b1r = 0.f;
  if (tid < H_) {
    hreg = hidden0[b * H_ + tid];
    b_ir = bih[tid]; b_iz = bih[200 + tid]; b_in = bih[400 + tid];
    b_hr = bhh[tid]; b_hz = bhh[200 + tid]; b_hn = bhh[400 + tid];
  }
  if (tid < A_) b1r = b1[tid];
  if (tid < 100) {
    h2 v;
    v[0] = (_Float16)hidden0[b * H_ + 2 * tid];
    v[1] = (_Float16)hidden0[b * H_ + 2 * tid + 1];
    h16[tid] = v;
  }
  for (int i = tid; i < AH2P; i += 512) {
    aW[i] = (i < A_) ? attn_W[i] : 0.f;
    s1[i] = 0.f;
  }
  h8 ah2row[13]; // b-row of ah2, t-invariant: cached in registers for all steps
  if (tid < S_) {
    const h8* src = (const h8*)(ah2h + ((size_t)b * S_ + tid) * AH2P);
#pragma unroll
    for (int r = 0; r < 13; ++r) ah2row[r] = src[r];
  }
  const float ab = attn_b[0];
  __syncthreads();

  const h8* W1h8 = (const h8*)W1h;
  const h8* Wihh8 = (const h8*)Wihh;
  const h8* Whhh8 = (const h8*)Whhh;

  for (int t = 0; t < T_; ++t) {
    // ---- phase 1: 800 units = 100 s1-dots + 100 xe-loads + 600 gh-dots
    for (int u = tid; u < 800; u += 512) {
      if (u < 100) {
        float acc = dot200h(W1h8, u, A_, (const h8*)h16);
        s1[u] = acc + b1r + ah3[((size_t)t * B_ + b) * A_ + u];
      } else if (u < 200) {
        const int j = u - 100;
        float2 e2 = *(const float2*)(emb + (size_t)tokL[t] * E_ + 2 * j);
        h2 v; v[0] = (_Float16)e2.x; v[1] = (_Float16)e2.y;
        xeh[j] = v;
      } else {
        const int r = u - 200;
        part[1200 + r] = dot200h(Whhh8, r, G3, (const h8*)h16);
      }
    }
    __syncthreads();

    // ---- phase 2: relu-attn logits from registers + softmax (tid<128)
    float p = -INFINITY;
    if (tid < S_) {
      float acc = ab;
#pragma unroll
      for (int r = 0; r < 13; ++r) {
        h8 w = ah2row[r];
#pragma unroll
        for (int j = 0; j < 8; ++j) {
          const int a = r * 8 + j;
          acc += fmaxf(s1[a] + (float)w[j], 0.f) * aW[a];
        }
      }
      p = acc;
    }
    float m = p;
#pragma unroll
    for (int off = 32; off > 0; off >>= 1) m = fmaxf(m, __shfl_xor(m, off, 64));
    if (tid < S_ && lane == 0) red[tid >> 6] = m;
    __syncthreads();
    const float M = fmaxf(red[0], red[1]);
    float ev = (tid < S_) ? expf(p - M) : 0.f;
    float sm = ev;
#pragma unroll
    for (int off = 32; off > 0; off >>= 1) sm += __shfl_xor(sm, off, 64);
    if (tid < S_ && lane == 0) red[4 + (tid >> 6)] = sm;
    __syncthreads();
    const float SS = red[4] + red[5];
    if (tid < S_) {
      const float av = ev / SS;
      out_attn[((size_t)t * B_ + b) * S_ + tid] = av;
      const float avn = __shfl_xor(av, 1, 64);
      if ((tid & 1) == 0) {
        h2 v; v[0] = (_Float16)av; v[1] = (_Float16)avn;
        aLh[tid >> 1] = v;
      }
    }
    __syncthreads();

    // ---- phase 3: ctx from LDS-resident encoder slice (tid<200)
    if (tid < H_) {
      const h8* er = (const h8*)(encLh + tid * ELD);
      float c0 = 0.f, c1 = 0.f, c2 = 0.f, c3 = 0.f;
#pragma unroll
      for (int k8 = 0; k8 < 16; ++k8) {
        h8 evv = er[k8];
        h2 ep[4];
        __builtin_memcpy(ep, &evv, 16);
        c0 = fdot2f(ep[0], aLh[4 * k8 + 0], c0);
        c1 = fdot2f(ep[1], aLh[4 * k8 + 1], c1);
        c2 = fdot2f(ep[2], aLh[4 * k8 + 2], c2);
        c3 = fdot2f(ep[3], aLh[4 * k8 + 3], c3);
      }
      const float c = (c0 + c1) + (c2 + c3);
      const float cn = __shfl_xor(c, 1, 64);
      if ((tid & 1) == 0) {
        h2 v; v[0] = (_Float16)c; v[1] = (_Float16)cn;
        xch[tid >> 1] = v;
      }
    }
    __syncthreads();

    // ---- phase 4: 1200 gi dot-units
    for (int u = tid; u < 1200; u += 512) {
      if (u < 600) part[u] = dot200h(Wihh8, u, G3, (const h8*)xeh);
      else part[u] = dot200h(Wihh8 + 25 * G3, u - 600, G3, (const h8*)xch);
    }
    __syncthreads();

    // ---- phase 5: gates + h update (tid<200)
    if (tid < H_) {
      const int n = tid;
      const float gir = part[n] + part[600 + n] + b_ir;
      const float giz = part[200 + n] + part[800 + n] + b_iz;
      const float gin = part[400 + n] + part[1000 + n] + b_in;
      const float ghr = part[1200 + n] + b_hr;
      const float ghz = part[1400 + n] + b_hz;
      const float ghn = part[1600 + n] + b_hn;
      const float r = 1.f / (1.f + expf(-(gir + ghr)));
      const float z = 1.f / (1.f + expf(-(giz + ghz)));
      const float nn = tanhf(gin + r * ghn);
      const float hv = (1.f - z) * nn + z * hreg;
      hreg = hv;
      hall[((size_t)t * B_ + b) * KP + n] = __float2bfloat16(hv);
      const float hn2 = __shfl_xor(hv, 1, 64);
      if ((tid & 1) == 0) {
        h2 v; v[0] = (_Float16)hv; v[1] = (_Float16)hn2;
        h16[tid >> 1] = v;
      }
      if (t == T_ - 1) out_hidden[b * H_ + n] = hv;
    }
    __syncthreads();
  }
}

// ---------------- batched output GEMM + log-softmax ----------------
__global__ __launch_bounds__(256) void k_big0(const short* __restrict__ hb,
                                              const short* __restrict__ wpk,
                                              const float* __restrict__ outb,
                                              float* __restrict__ pmax,
                                              float* __restrict__ psum) {
  const int tid = threadIdx.x;
  const int w = tid >> 6, l = tid & 63;
  const int lm = l & 15, lg = l >> 4;
  const int r0 = blockIdx.y * 64;
  const int v0 = blockIdx.x * 256 + w * 64;

  f32x4 acc[4][4] = {};
#pragma unroll
  for (int kt = 0; kt < KP / 32; ++kt) {
    const int k0 = kt * 32;
    bf16x8 af[4], bfr[4];
#pragma unroll
    for (int wm = 0; wm < 4; ++wm)
      af[wm] = *(const bf16x8*)(hb + (size_t)(r0 + wm * 16 + lm) * KP + k0 + lg * 8);
#pragma unroll
    for (int n = 0; n < 4; ++n)
      bfr[n] = *(const bf16x8*)(wpk + ((size_t)((k0 >> 3) + lg) * VP + v0 + n * 16 + lm) * 8);
#pragma unroll
    for (int wm = 0; wm < 4; ++wm)
#pragma unroll
      for (int n = 0; n < 4; ++n)
        acc[wm][n] = __builtin_amdgcn_mfma_f32_16x16x32_bf16(af[wm], bfr[n], acc[wm][n], 0, 0, 0);
  }

  int vv[4]; float bias[4]; bool val[4];
#pragma unroll
  for (int n = 0; n < 4; ++n) {
    vv[n] = v0 + n * 16 + lm;
    val[n] = vv[n] < V_;
    bias[n] = val[n] ? outb[vv[n]] : 0.f;
  }

  __shared__ float smax[4][64], ssum[4][64];
#pragma unroll
  for (int wm = 0; wm < 4; ++wm) {
#pragma unroll
    for (int j = 0; j < 4; ++j) {
      float mv = -INFINITY;
#pragma unroll
      for (int n = 0; n < 4; ++n)
        if (val[n]) mv = fmaxf(mv, acc[wm][n][j] + bias[n]);
      for (int off = 8; off > 0; off >>= 1) mv = fmaxf(mv, __shfl_xor(mv, off, 64));
      float sv = 0.f;
#pragma unroll
      for (int n = 0; n < 4; ++n)
        if (val[n]) sv += expf(acc[wm][n][j] + bias[n] - mv);
      for (int off = 8; off > 0; off >>= 1) sv += __shfl_xor(sv, off, 64);
      if (lm == 0) {
        smax[w][wm * 16 + lg * 4 + j] = mv;
        ssum[w][wm * 16 + lg * 4 + j] = sv;
      }
    }
  }
  __syncthreads();
  if (tid < 64) {
    float mv = -INFINITY;
    for (int ww = 0; ww < 4; ++ww) mv = fmaxf(mv, smax[ww][tid]);
    float sv = 0.f;
    for (int ww = 0; ww < 4; ++ww) {
      float sw = ssum[ww][tid];
      if (sw > 0.f) sv += expf(smax[ww][tid] - mv) * sw;
    }
    pmax[(size_t)blockIdx.x * MROWS + r0 + tid] = mv;
    psum[(size_t)blockIdx.x * MROWS + r0 + tid] = sv;
  }
}

__global__ __launch_bounds__(256) void k_lse(const float* __restrict__ pmax,
                                             const float* __restrict__ psum,
                                             float* __restrict__ lse) {
  const int r = blockIdx.x * 256 + threadIdx.x;
  float mv = -INFINITY;
  for (int c = 0; c < NCB; ++c) mv = fmaxf(mv, pmax[(size_t)c * MROWS + r]);
  float sv = 0.f;
  for (int c = 0; c < NCB; ++c) {
    float sw = psum[(size_t)c * MROWS + r];
    if (sw > 0.f) sv += expf(pmax[(size_t)c * MROWS + r] - mv) * sw;
  }
  lse[r] = mv + logf(sv);
}

__global__ __launch_bounds__(256) void k_big1(const short* __restrict__ hb,
                                              const short* __restrict__ wpk,
                                              const float* __restrict__ outb,
                                              const float* __restrict__ lse,
                                              float* __restrict__ out_logp) {
  const int tid = threadIdx.x;
  const int w = tid >> 6, l = tid & 63;
  const int lm = l & 15, lg = l >> 4;
  const int r0 = blockIdx.y * 64;
  const int v0 = blockIdx.x * 256 + w * 64;

  __shared__ float lseL[64];
  if (tid < 64) lseL[tid] = lse[r0 + tid];

  f32x4 acc[4][4] = {};
#pragma unroll
  for (int kt = 0; kt < KP / 32; ++kt) {
    const int k0 = kt * 32;
    bf16x8 af[4], bfr[4];
#pragma unroll
    for (int wm = 0; wm < 4; ++wm)
      af[wm] = *(const bf16x8*)(hb + (size_t)(r0 + wm * 16 + lm) * KP + k0 + lg * 8);
#pragma unroll
    for (int n = 0; n < 4; ++n)
      bfr[n] = *(const bf16x8*)(wpk + ((size_t)((k0 >> 3) + lg) * VP + v0 + n * 16 + lm) * 8);
#pragma unroll
    for (int wm = 0; wm < 4; ++wm)
#pragma unroll
      for (int n = 0; n < 4; ++n)
        acc[wm][n] = __builtin_amdgcn_mfma_f32_16x16x32_bf16(af[wm], bfr[n], acc[wm][n], 0, 0, 0);
  }

  int vv[4]; float bias[4]; bool val[4];
#pragma unroll
  for (int n = 0; n < 4; ++n) {
    vv[n] = v0 + n * 16 + lm;
    val[n] = vv[n] < V_;
    bias[n] = val[n] ? outb[vv[n]] : 0.f;
  }
  __syncthreads();
#pragma unroll
  for (int wm = 0; wm < 4; ++wm) {
#pragma unroll
    for (int j = 0; j < 4; ++j) {
      const int row = r0 + wm * 16 + lg * 4 + j;
      const float ls = lseL[wm * 16 + lg * 4 + j];
#pragma unroll
      for (int n = 0; n < 4; ++n)
        if (val[n]) out_logp[(size_t)row * V_ + vv[n]] = acc[wm][n][j] + bias[n] - ls;
    }
  }
}

// ---------------- host launch ----------------

extern "C" void kernel_launch(void* const* d_in, const int* in_sizes, int n_in,
                              void* d_out, int out_size, void* d_ws, size_t ws_size,
                              hipStream_t stream) {
  (void)in_sizes; (void)n_in; (void)out_size; (void)ws_size;
  const int* tokens = (const int*)d_in[0];
  const float* hidden0 = (const float*)d_in[1];
  const float* encoder = (const float*)d_in[2];
  const float* emb = (const float*)d_in[3];
  const float* W1 = (const float*)d_in[4];
  const float* b1 = (const float*)d_in[5];
  const float* W2 = (const float*)d_in[6];
  const float* b2 = (const float*)d_in[7];
  const float* W3 = (const float*)d_in[8];
  const float* b3 = (const float*)d_in[9];
  const float* attn_W = (const float*)d_in[10];
  const float* attn_b = (const float*)d_in[11];
  const float* Wih = (const float*)d_in[12];
  const float* Whh = (const float*)d_in[13];
  const float* bih = (const float*)d_in[14];
  const float* bhh = (const float*)d_in[15];
  const float* outW = (const float*)d_in[16];
  const float* outb = (const float*)d_in[17];

  float* out_logp = (float*)d_out;                       // [T*B, V]
  float* out_hidden = out_logp + (size_t)T_ * B_ * V_;   // [B, H]
  float* out_attn = out_hidden + (size_t)B_ * H_;        // [T, B, S]

  float* ws = (float*)d_ws;
  float* ah3w = ws;                                      // T*B*A
  float* pmaxw = ah3w + (size_t)T_ * B_ * A_;            // NCB*MROWS
  float* psumw = pmaxw + (size_t)NCB * MROWS;            // NCB*MROWS
  float* lsew = psumw + (size_t)NCB * MROWS;             // MROWS
  __hip_bfloat16* hallw = (__hip_bfloat16*)(lsew + MROWS);    // MROWS*KP
  __hip_bfloat16* wpkw = hallw + (size_t)MROWS * KP;          // (KP/8)*VP*8
  _Float16* ah2hw = (_Float16*)(wpkw + (size_t)(KP / 8) * VP * 8); // B*S*AH2P
  _Float16* W1hw = ah2hw + (size_t)B_ * S_ * AH2P;            // 25*A*8
  _Float16* Wihhw = W1hw + (size_t)25 * A_ * 8;               // 50*G3*8
  _Float16* Whhhw = Wihhw + (size_t)50 * G3 * 8;              // 25*G3*8

  k_pack<<<512, 256, 0, stream>>>(outW, W1, Wih, Whh, wpkw, hallw, W1hw, Wihhw, Whhhw);
  k_ah2<<<dim3(S_, B_ / 16), 256, 0, stream>>>(encoder, W2, b2, ah2hw);
  k_ah3<<<dim3(T_, B_ / 16), 256, 0, stream>>>(tokens, emb, W3, b3, ah3w);

  k_recur<<<B_, 512, 0, stream>>>(hidden0, ah2hw, ah3w, encoder, W1hw, b1, attn_W, attn_b,
                                  tokens, emb, Wihhw, Whhhw, bih, bhh,
                                  hallw, out_hidden, out_attn);

  k_big0<<<dim3(NCB, MROWS / 64), 256, 0, stream>>>((const short*)hallw, (const short*)wpkw,
                                                    outb, pmaxw, psumw);
  k_lse<<<MROWS / 256, 256, 0, stream>>>(pmaxw, psumw, lsew);
  k_big1<<<dim3(NCB, MROWS / 64), 256, 0, stream>>>((const short*)hallw, (const short*)wpkw,
                                                    outb, lsew, out_logp);
}